// Round 14
// baseline (3136.508 us; speedup 1.0000x reference)
//
#include <hip/hip_runtime.h>
#include <hip/hip_bf16.h>
#include <cstdint>
#include <cstddef>

// ---------- types ----------
typedef __attribute__((ext_vector_type(8))) short  bf16x8;
typedef __attribute__((ext_vector_type(4))) float  f32x4;
typedef __attribute__((ext_vector_type(4))) ushort u16x4;
typedef __attribute__((ext_vector_type(8))) ushort u16x8;

#define MFMA16(a, b, c) __builtin_amdgcn_mfma_f32_16x16x32_bf16((a), (b), (c), 0, 0, 0)

__device__ __forceinline__ ushort f2b(float x) {
    union { float f; uint32_t u; } c; c.f = x;
    uint32_t u = c.u + 0x7fffu + ((c.u >> 16) & 1u);   // RNE
    return (ushort)(u >> 16);
}

__device__ __forceinline__ void gload_lds16(const ushort* g, ushort* l) {
    __builtin_amdgcn_global_load_lds((const __attribute__((address_space(1))) void*)g,
                                     (__attribute__((address_space(3))) void*)l, 16, 0, 0);
}

__device__ __forceinline__ float gelu_f(float xx) {
    const float a = 0.7978845608f * (xx + 0.044715f * xx * xx * xx);
    const float t2 = 1.0f - 2.0f / (1.0f + __expf(2.0f * a));   // tanh(a)
    return 0.5f * xx * (1.0f + t2);
}

// ---------- 8-wave phase-interleaved GEMM (T3+T4+T5; r13-proven) ----------
// BM x 128 tile, BK=32, 8 waves, 3 LDS buffers. Per K-tile:
//   {counted vmcnt(PER); barrier} then 2 phases, each
//   {ds_read frags || issue stage chunks of tile t+2; barrier; setprio1;
//    MFMA cluster; setprio0; barrier}.
// BM=256: 4Mx2N waves (per-wave 64x64), PER=3. BM=128: 2Mx4N (64x32), PER=2.
// Staging/read lane maps are the r7-proven conflict-free XOR chunks.
template<int BM, int OUTBF, int RES, int GELU>
__global__ __launch_bounds__(512)
void gemm8p(const ushort* __restrict__ A, const ushort* __restrict__ W,
            const float* __restrict__ bias, const float* resid, void* outp,
            int M, int N, int K, int gx)
{
    constexpr int NCA = BM / 16;            // A chunks per K-tile (16 or 8)
    constexpr int NCB = 8;                  // B chunks (BN=128)
    constexpr int PER = (NCA + NCB) / 8;    // loads per wave per K-tile (3 or 2)
    constexpr int WM  = (BM == 256) ? 4 : 2;
    constexpr int WN  = 8 / WM;
    constexpr int NI  = BM / 16 / WM;       // 4 in both configs
    constexpr int NJ  = 128 / 16 / WN;      // 4 (BM=256) or 2 (BM=128)
    __shared__ __align__(16) ushort Als[3][NCA * 512];
    __shared__ __align__(16) ushort Bls[3][NCB * 512];

    const int tid  = threadIdx.x;
    const int lane = tid & 63, wid = tid >> 6;          // 8 waves

    // bijective XCD-aware swizzle (m204)
    const int nwg  = gridDim.x;
    const int orig = blockIdx.x;
    const int xcd = orig & 7, local = orig >> 3;
    const int q8 = nwg >> 3, r8 = nwg & 7;
    const int swz = (xcd < r8 ? xcd * (q8 + 1) : r8 * (q8 + 1) + (xcd - r8) * q8) + local;
    const int bx = swz % gx, by = swz / gx;

    const int m0 = by * BM, n0 = bx * 128;
    const int wr = wid / WN, wc = wid % WN;
    const int ecol = lane & 15, eg = lane >> 4;

    // r7-proven staging map: lane l -> slot l; fetch (row,kc) = dec of swizzle
    const int dec  = lane ^ ((lane >> 3) & 7);
    const int srow = dec >> 2;
    const int scol = (dec & 3) * 8;
    const int sfrag = ecol * 4 + eg;
    const int swslot = sfrag ^ ((sfrag >> 3) & 7);

    f32x4 acc[NI][NJ] = {};

    // chunks: A q=0..NCA-1 (rows q*16), B q=NCA..NCA+7. Wave w owns
    // q = w*PER .. w*PER+PER-1; staged cbeg..cend per phase.
    auto stage = [&](int p, int k0, int cbeg, int cend) {
        for (int c = cbeg; c <= cend; ++c) {
            const int q = wid * PER + c;
            if (q < NCA) {
                int ga = m0 + q * 16 + srow; if (ga > M - 1) ga = M - 1;   // clamp
                gload_lds16(A + (size_t)ga * K + k0 + scol, &Als[p][q * 512]);
            } else {
                const int rg = q - NCA;
                gload_lds16(W + (size_t)(n0 + rg * 16 + srow) * K + k0 + scol,
                            &Bls[p][rg * 512]);
            }
        }
    };

    const int NT = K >> 5;                 // BK=32
    stage(0, 0, 0, PER - 1);
    stage(1, 32, 0, PER - 1);

    for (int t = 0; t < NT; ++t) {
        if (t + 1 < NT) asm volatile("s_waitcnt vmcnt(%0)" :: "n"(PER) : "memory");
        else            asm volatile("s_waitcnt vmcnt(0)" ::: "memory");
        __builtin_amdgcn_s_barrier();
        const int cur = t % 3;
        const int nxt = (t + 2) % 3;
        const int k2  = (t + 2) << 5;
        const bool st = (t + 2) < NT;
#pragma unroll
        for (int ph = 0; ph < 2; ++ph) {
            const int i0 = ph * (NI / 2);
            bf16x8 af[NI / 2], bfr[NJ];
#pragma unroll
            for (int i = 0; i < NI / 2; ++i)
                af[i] = *(const bf16x8*)&Als[cur][(wr * NI + i0 + i) * 512 + swslot * 8];
#pragma unroll
            for (int j = 0; j < NJ; ++j)
                bfr[j] = *(const bf16x8*)&Bls[cur][(wc * NJ + j) * 512 + swslot * 8];
            if (st) {
                if (ph == 0) stage(nxt, k2, 0, PER == 3 ? 1 : 0);
                else         stage(nxt, k2, PER == 3 ? 2 : 1, PER - 1);
            }
            __builtin_amdgcn_s_barrier();
            __builtin_amdgcn_s_setprio(1);
#pragma unroll
            for (int i = 0; i < NI / 2; ++i)
#pragma unroll
                for (int j = 0; j < NJ; ++j)
                    acc[i0 + i][j] = MFMA16(af[i], bfr[j], acc[i0 + i][j]);
            __builtin_amdgcn_s_setprio(0);
            if (ph == 0) __builtin_amdgcn_s_barrier();
        }
    }

#pragma unroll
    for (int i = 0; i < NI; ++i) {
        const int mb = m0 + wr * (NI * 16) + i * 16 + eg * 4;
#pragma unroll
        for (int j = 0; j < NJ; ++j) {
            const int n = n0 + wc * (NJ * 16) + j * 16 + ecol;
            const float bv = bias[n];
#pragma unroll
            for (int r = 0; r < 4; ++r) {
                const int m = mb + r;
                if (m < M) {
                    float v = acc[i][j][r] + bv;
                    if (RES)  v += resid[(size_t)m * N + n];
                    if (GELU) v = gelu_f(v);
                    if (OUTBF) ((ushort*)outp)[(size_t)m * N + n] = f2b(v);
                    else       ((float*)outp)[(size_t)m * N + n]  = v;
                }
            }
        }
    }
}

// ---------- 4-wave 2-phase GEMM (r10-proven; patch embed only) ----------
template<int BM, int BN, int OUTBF, int RES, int GELU>
__global__ __launch_bounds__(256)
void gemm_bt(const ushort* __restrict__ A, const ushort* __restrict__ W,
             const float* __restrict__ bias, const float* resid,
             void* outp, int M, int N, int K, int gx)
{
    constexpr int NI   = BM / 32;
    constexpr int NJ   = BN / 32;
    constexpr int NCHA = BM / 16;
    constexpr int NCHB = BN / 16;
    constexpr int NCH  = 2 * (NCHA + NCHB);
    constexpr int PER  = NCH / 4;
    __shared__ __align__(16) ushort Als[2][2 * NCHA * 512];
    __shared__ __align__(16) ushort Bls[2][2 * NCHB * 512];

    const int tid  = threadIdx.x;
    const int lane = tid & 63, wid = tid >> 6;

    const int nwg  = gridDim.x;
    const int orig = blockIdx.x;
    const int xcd = orig & 7, local = orig >> 3;
    const int q8 = nwg >> 3, r8 = nwg & 7;
    const int swz = (xcd < r8 ? xcd * (q8 + 1) : r8 * (q8 + 1) + (xcd - r8) * q8) + local;
    const int bx = swz % gx, by = swz / gx;

    const int m0 = by * BM, n0 = bx * BN;
    const int wr = wid >> 1, wc = wid & 1;
    const int ecol = lane & 15, eg = lane >> 4;

    const int dec  = lane ^ ((lane >> 3) & 7);
    const int srow = dec >> 2;
    const int scol = (dec & 3) * 8;
    const int sfrag = ecol * 4 + eg;
    const int swslot = sfrag ^ ((sfrag >> 3) & 7);

    f32x4 acc[NI][NJ] = {};

    auto stage = [&](int p, int k0) {
#pragma unroll
        for (int c = 0; c < PER; ++c) {
            const int q = wid * PER + c;
            if (q < 2 * NCHA) {
                const int rg = q >> 1, kh = q & 1;
                int ga = m0 + rg * 16 + srow; if (ga > M - 1) ga = M - 1;
                gload_lds16(A + (size_t)ga * K + k0 + kh * 32 + scol, &Als[p][q * 512]);
            } else {
                const int qq = q - 2 * NCHA;
                const int rg = qq >> 1, kh = qq & 1;
                gload_lds16(W + (size_t)(n0 + rg * 16 + srow) * K + k0 + kh * 32 + scol,
                            &Bls[p][qq * 512]);
            }
        }
    };

    const int NT = K >> 6;
    stage(0, 0);
    __syncthreads();

    int cur = 0;
    for (int t = 0; t < NT; ++t) {
        if (t + 1 < NT) stage(cur ^ 1, (t + 1) << 6);
#pragma unroll
        for (int kk = 0; kk < 2; ++kk) {
            bf16x8 af[NI], bfr[NJ];
#pragma unroll
            for (int i = 0; i < NI; ++i)
                af[i] = *(const bf16x8*)&Als[cur][(((wr * NI + i) << 1) + kk) * 512 + swslot * 8];
#pragma unroll
            for (int j = 0; j < NJ; ++j)
                bfr[j] = *(const bf16x8*)&Bls[cur][(((wc * NJ + j) << 1) + kk) * 512 + swslot * 8];
#pragma unroll
            for (int i = 0; i < NI; ++i)
#pragma unroll
                for (int j = 0; j < NJ; ++j)
                    acc[i][j] = MFMA16(af[i], bfr[j], acc[i][j]);
        }
        if (t + 1 < NT) __syncthreads();
        cur ^= 1;
    }

#pragma unroll
    for (int i = 0; i < NI; ++i) {
        const int mb = m0 + wr * (BM / 2) + i * 16 + eg * 4;
#pragma unroll
        for (int j = 0; j < NJ; ++j) {
            const int n = n0 + wc * (BN / 2) + j * 16 + ecol;
            const float bv = bias[n];
#pragma unroll
            for (int r = 0; r < 4; ++r) {
                const int m = mb + r;
                if (m < M) {
                    float v = acc[i][j][r] + bv;
                    if (RES)  v += resid[(size_t)m * N + n];
                    if (GELU) v = gelu_f(v);
                    if (OUTBF) ((ushort*)outp)[(size_t)m * N + n] = f2b(v);
                    else       ((float*)outp)[(size_t)m * N + n]  = v;
                }
            }
        }
    }
}

// ---------- attention: one block per (b, head), 4 waves, q-tiles of 16 ----------
__global__ __launch_bounds__(256)
void attn_k(const ushort* __restrict__ qkv, ushort* __restrict__ o)
{
    __shared__ __align__(16) ushort Vt[64][224];
    __shared__ __align__(16) ushort Pb[4][16][224];
    const int bh = blockIdx.x;
    const int b = bh / 12, hh = bh % 12;
    const int tid = threadIdx.x, lane = tid & 63, wid = tid >> 6;
    const size_t rs = 2304;
    const ushort* qb = qkv + (size_t)b * 197 * rs + hh * 64;
    const ushort* kb = qb + 768;
    const ushort* vb = qb + 1536;

    for (int i = tid; i < 197 * 64; i += 256) {
        const int s = i >> 6, d = i & 63;
        Vt[d][s] = vb[(size_t)s * rs + d];
    }
    for (int i = tid; i < 64 * 27; i += 256) {
        const int d = i / 27, s = 197 + i % 27;
        Vt[d][s] = 0;
    }
    __syncthreads();

    const int ecol = lane & 15, eg = lane >> 4;
    const bool m12bad = (192 + ecol) > 196;

    for (int qt = wid; qt < 13; qt += 4) {
        int qrow = qt * 16 + ecol; if (qrow > 196) qrow = 196;
        bf16x8 qa0 = *(const bf16x8*)&qb[(size_t)qrow * rs + eg * 8];
        bf16x8 qa1 = *(const bf16x8*)&qb[(size_t)qrow * rs + 32 + eg * 8];

        f32x4 s[13];
#pragma unroll
        for (int kt = 0; kt < 13; ++kt) {
            int krow = kt * 16 + ecol; if (krow > 196) krow = 196;
            bf16x8 kf0 = *(const bf16x8*)&kb[(size_t)krow * rs + eg * 8];
            bf16x8 kf1 = *(const bf16x8*)&kb[(size_t)krow * rs + 32 + eg * 8];
            f32x4 a = {};
            a = MFMA16(qa0, kf0, a);
            a = MFMA16(qa1, kf1, a);
            s[kt] = a;
        }
#pragma unroll
        for (int kt = 0; kt < 13; ++kt)
#pragma unroll
            for (int r = 0; r < 4; ++r) s[kt][r] *= 0.125f;
        if (m12bad) { s[12][0] = -1e30f; s[12][1] = -1e30f; s[12][2] = -1e30f; s[12][3] = -1e30f; }

#pragma unroll
        for (int r = 0; r < 4; ++r) {
            float mx = s[0][r];
#pragma unroll
            for (int kt = 1; kt < 13; ++kt) mx = fmaxf(mx, s[kt][r]);
#pragma unroll
            for (int off = 1; off < 16; off <<= 1) mx = fmaxf(mx, __shfl_xor(mx, off));
            float sm = 0.0f;
#pragma unroll
            for (int kt = 0; kt < 13; ++kt) { float e = __expf(s[kt][r] - mx); s[kt][r] = e; sm += e; }
#pragma unroll
            for (int off = 1; off < 16; off <<= 1) sm += __shfl_xor(sm, off);
            const float inv = 1.0f / sm;
#pragma unroll
            for (int kt = 0; kt < 13; ++kt) s[kt][r] *= inv;
        }

#pragma unroll
        for (int kt = 0; kt < 13; ++kt)
#pragma unroll
            for (int r = 0; r < 4; ++r)
                Pb[wid][eg * 4 + r][kt * 16 + ecol] = f2b(s[kt][r]);
#pragma unroll
        for (int r = 0; r < 4; ++r) Pb[wid][eg * 4 + r][208 + ecol] = 0;
        asm volatile("s_waitcnt lgkmcnt(0)" ::: "memory");
        __builtin_amdgcn_sched_barrier(0);

        f32x4 oacc[4] = {};
#pragma unroll
        for (int ks = 0; ks < 7; ++ks) {
            bf16x8 pa = *(const bf16x8*)&Pb[wid][ecol][ks * 32 + eg * 8];
#pragma unroll
            for (int dt = 0; dt < 4; ++dt) {
                bf16x8 vf = *(const bf16x8*)&Vt[dt * 16 + ecol][ks * 32 + eg * 8];
                oacc[dt] = MFMA16(pa, vf, oacc[dt]);
            }
        }
#pragma unroll
        for (int dt = 0; dt < 4; ++dt)
#pragma unroll
            for (int r = 0; r < 4; ++r) {
                const int q = qt * 16 + eg * 4 + r;
                if (q < 197)
                    o[((size_t)(b * 197 + q)) * 768 + hh * 64 + dt * 16 + ecol] = f2b(oacc[dt][r]);
            }
        asm volatile("s_waitcnt lgkmcnt(0)" ::: "memory");
        __builtin_amdgcn_sched_barrier(0);
    }
}

// ---------- LayerNorm (f32 in, bf16 out), one wave per row of 768 ----------
__global__ __launch_bounds__(256)
void ln_k(const float* __restrict__ x, const float* __restrict__ g,
          const float* __restrict__ bta, ushort* __restrict__ y, int rows)
{
    const int row  = blockIdx.x * 4 + (threadIdx.x >> 6);
    const int lane = threadIdx.x & 63;
    if (row >= rows) return;
    const float* xr = x + (size_t)row * 768;
    f32x4 v[3];
#pragma unroll
    for (int t = 0; t < 3; ++t) v[t] = *(const f32x4*)&xr[(lane + t * 64) * 4];
    float s = 0.0f;
#pragma unroll
    for (int t = 0; t < 3; ++t) s += v[t][0] + v[t][1] + v[t][2] + v[t][3];
#pragma unroll
    for (int off = 1; off < 64; off <<= 1) s += __shfl_xor(s, off);
    const float mean = s * (1.0f / 768.0f);
    float sq = 0.0f;
#pragma unroll
    for (int t = 0; t < 3; ++t)
#pragma unroll
        for (int c = 0; c < 4; ++c) { const float d = v[t][c] - mean; sq += d * d; }
#pragma unroll
    for (int off = 1; off < 64; off <<= 1) sq += __shfl_xor(sq, off);
    const float rstd = rsqrtf(sq * (1.0f / 768.0f) + 1e-5f);
    ushort* yr = y + (size_t)row * 768;
#pragma unroll
    for (int t = 0; t < 3; ++t) {
        const int c0 = (lane + t * 64) * 4;
        f32x4 gw = *(const f32x4*)&g[c0];
        f32x4 bb = *(const f32x4*)&bta[c0];
        u16x4 ov;
#pragma unroll
        for (int c = 0; c < 4; ++c) ov[c] = f2b((v[t][c] - mean) * rstd * gw[c] + bb[c]);
        *(u16x4*)&yr[c0] = ov;
    }
}

// ---------- im2col: x f32 -> patches bf16 [6272][768] ----------
__global__ void im2col_k(const float* __restrict__ x, ushort* __restrict__ p)
{
    const int gid = blockIdx.x * 256 + threadIdx.x;
    if (gid >= 6272 * 768) return;
    const int m = gid / 768, idx = gid - m * 768;
    const int b = m / 196, t = m - b * 196;
    const int gy = t / 14, gx = t - gy * 14;
    const int c = idx >> 8, rr = idx & 255;
    const int py = rr >> 4, px = rr & 15;
    const float v = x[(((size_t)(b * 3 + c) * 224) + gy * 16 + py) * 224 + gx * 16 + px];
    p[gid] = f2b(v);
}

// ---------- assemble: h = concat(cls, emb) + pos (all f32) ----------
__global__ void assemble_k(const float* __restrict__ emb, const float* __restrict__ cls,
                           const float* __restrict__ pos, float* __restrict__ h)
{
    const int gid = blockIdx.x * 256 + threadIdx.x;
    if (gid >= 6304 * 192) return;
    const int r = gid / 192, c4 = gid - r * 192;
    const int b = r / 197, s = r - b * 197;
    f32x4 pe = *(const f32x4*)&pos[(s * 192 + c4) * 4];
    f32x4 sv;
    if (s == 0) sv = *(const f32x4*)&cls[c4 * 4];
    else        sv = *(const f32x4*)&emb[((size_t)(b * 196 + (s - 1)) * 192 + c4) * 4];
    f32x4 ov = pe + sv;
    *(f32x4*)&h[(size_t)gid * 4] = ov;
}

// ---------- generic f32 -> bf16 convert (8 elems/thread) ----------
__global__ void cvt_k(const float* __restrict__ src, ushort* __restrict__ dst, int n8)
{
    const int g = blockIdx.x * 256 + threadIdx.x;
    if (g >= n8) return;
    const int e = g * 8;
    f32x4 a = *(const f32x4*)&src[e];
    f32x4 b = *(const f32x4*)&src[e + 4];
    u16x8 ov;
#pragma unroll
    for (int c = 0; c < 4; ++c) { ov[c] = f2b(a[c]); ov[4 + c] = f2b(b[c]); }
    *(u16x8*)&dst[e] = ov;
}

// ---------- fused per-layer weight convert: 6 tensors -> wbuf bf16 ----------
__global__ void conv6_k(const float* __restrict__ s0, const float* __restrict__ s1,
                        const float* __restrict__ s2, const float* __restrict__ s3,
                        const float* __restrict__ s4, const float* __restrict__ s5,
                        ushort* __restrict__ dst)
{
    const int g = blockIdx.x * 256 + threadIdx.x;
    if (g >= 884736) return;
    const int e = g * 8;
    const float* src; int off;
    if      (e < 589824)  { src = s0; off = e; }
    else if (e < 1179648) { src = s1; off = e - 589824; }
    else if (e < 1769472) { src = s2; off = e - 1179648; }
    else if (e < 2359296) { src = s3; off = e - 1769472; }
    else if (e < 4718592) { src = s4; off = e - 2359296; }
    else                  { src = s5; off = e - 4718592; }
    f32x4 a = *(const f32x4*)&src[off];
    f32x4 b = *(const f32x4*)&src[off + 4];
    u16x8 ov;
#pragma unroll
    for (int c = 0; c < 4; ++c) { ov[c] = f2b(a[c]); ov[4 + c] = f2b(b[c]); }
    *(u16x8*)&dst[e] = ov;
}

// ---------- concat qkv biases ----------
__global__ void bias3_k(const float* __restrict__ b0, const float* __restrict__ b1,
                        const float* __restrict__ b2, float* __restrict__ dst)
{
    const int i = blockIdx.x * 256 + threadIdx.x;
    if (i >= 2304) return;
    dst[i] = (i < 768) ? b0[i] : (i < 1536 ? b1[i - 768] : b2[i - 1536]);
}

// ---------- classifier: logits[b,n] from h[b*197] row, f32 out ----------
__global__ __launch_bounds__(64)
void clf_k(const float* __restrict__ h, const float* __restrict__ w,
           const float* __restrict__ bias, float* __restrict__ out)
{
    const int b = blockIdx.x, lane = threadIdx.x;
    const float* hr = h + (size_t)b * 197 * 768;
    float hv[12];
#pragma unroll
    for (int j = 0; j < 12; ++j) hv[j] = hr[lane + j * 64];
    for (int n = 0; n < 14; ++n) {
        float sm = 0.0f;
#pragma unroll
        for (int j = 0; j < 12; ++j) sm += hv[j] * w[n * 768 + lane + j * 64];
#pragma unroll
        for (int off = 1; off < 64; off <<= 1) sm += __shfl_xor(sm, off);
        if (lane == 0) out[b * 14 + n] = sm + bias[n];
    }
}

// ---------- launcher ----------
extern "C" void kernel_launch(void* const* d_in, const int* in_sizes, int n_in,
                              void* d_out, int out_size, void* d_ws, size_t ws_size,
                              hipStream_t stream)
{
    const float* x       = (const float*)d_in[0];
    const float* patch_w = (const float*)d_in[1];
    const float* patch_b = (const float*)d_in[2];
    const float* cls_tok = (const float*)d_in[3];
    const float* pos_emb = (const float*)d_in[4];
    const float* ln1_w   = (const float*)d_in[5];
    const float* ln1_b   = (const float*)d_in[6];
    const float* wq      = (const float*)d_in[7];
    const float* bq      = (const float*)d_in[8];
    const float* wk      = (const float*)d_in[9];
    const float* bk      = (const float*)d_in[10];
    const float* wv      = (const float*)d_in[11];
    const float* bv      = (const float*)d_in[12];
    const float* wo      = (const float*)d_in[13];
    const float* bo      = (const float*)d_in[14];
    const float* ln2_w   = (const float*)d_in[15];
    const float* ln2_b   = (const float*)d_in[16];
    const float* fc1w    = (const float*)d_in[17];
    const float* fc1b    = (const float*)d_in[18];
    const float* fc2w    = (const float*)d_in[19];
    const float* fc2b    = (const float*)d_in[20];
    const float* clfw    = (const float*)d_in[21];
    const float* clfb    = (const float*)d_in[22];

    char* ws = (char*)d_ws;
    float*  h    = (float*)(ws + 0);                    // 6304*768 f32
    ushort* y    = (ushort*)(ws + 19365888);            // 6304*768 bf16
    ushort* qkv  = (ushort*)(ws + 29048832);            // 6304*2304 bf16
    ushort* o    = (ushort*)(ws + 58097664);            // 6304*768 bf16
    ushort* ff   = (ushort*)(ws + 67780608);            // 6304*3072 bf16
    ushort* wbuf = (ushort*)(ws + 106512384);           // 7,077,888 bf16 (per-layer)
    float*  b3   = (float*)(ws + 120668160);            // 2304 f32
    ushort* patches = (ushort*)(ws + 67780608);         // alias ff (used pre-loop)
    float*  emb     = (float*)(ws + 67780608 + 16777216); // alias ff+16MB

    // patch embed
    im2col_k<<<18816, 256, 0, stream>>>(x, patches);
    cvt_k<<<288, 256, 0, stream>>>(patch_w, wbuf, 73728);
    gemm_bt<128, 64, 0, 0, 0><<<12 * 49, 256, 0, stream>>>(patches, wbuf, patch_b,
                                                      (const float*)nullptr, (void*)emb, 6272, 768, 768, 12);
    assemble_k<<<4728, 256, 0, stream>>>(emb, cls_tok, pos_emb, h);

    for (int l = 0; l < 12; ++l) {
        conv6_k<<<3456, 256, 0, stream>>>(wq + (size_t)l * 589824, wk + (size_t)l * 589824,
                                          wv + (size_t)l * 589824, wo + (size_t)l * 589824,
                                          fc1w + (size_t)l * 2359296, fc2w + (size_t)l * 2359296, wbuf);
        bias3_k<<<9, 256, 0, stream>>>(bq + l * 768, bk + l * 768, bv + l * 768, b3);
        ln_k<<<1576, 256, 0, stream>>>(h, ln1_w + l * 768, ln1_b + l * 768, y, 6304);
        gemm8p<256, 1, 0, 0><<<18 * 25, 512, 0, stream>>>(y, wbuf, b3,
                                                          (const float*)nullptr, (void*)qkv, 6304, 2304, 768, 18);
        attn_k<<<384, 256, 0, stream>>>(qkv, o);
        gemm8p<128, 0, 1, 0><<<6 * 50, 512, 0, stream>>>(o, wbuf + 1769472, bo + l * 768,
                                                         (const float*)h, (void*)h, 6304, 768, 768, 6);
        ln_k<<<1576, 256, 0, stream>>>(h, ln2_w + l * 768, ln2_b + l * 768, y, 6304);
        gemm8p<256, 1, 0, 1><<<24 * 25, 512, 0, stream>>>(y, wbuf + 2359296, fc1b + (size_t)l * 3072,
                                                          (const float*)nullptr, (void*)ff, 6304, 3072, 768, 24);
        gemm8p<128, 0, 1, 0><<<6 * 50, 512, 0, stream>>>(ff, wbuf + 4718592, fc2b + l * 768,
                                                         (const float*)h, (void*)h, 6304, 768, 3072, 6);
    }
    clf_k<<<32, 64, 0, stream>>>(h, clfw, clfb, (float*)d_out);
}

// Round 15
// 3094.306 us; speedup vs baseline: 1.0136x; 1.0136x over previous
//
#include <hip/hip_runtime.h>
#include <hip/hip_bf16.h>
#include <cstdint>
#include <cstddef>

// ---------- types ----------
typedef __attribute__((ext_vector_type(8))) short  bf16x8;
typedef __attribute__((ext_vector_type(4))) float  f32x4;
typedef __attribute__((ext_vector_type(4))) ushort u16x4;
typedef __attribute__((ext_vector_type(8))) ushort u16x8;

#define MFMA16(a, b, c) __builtin_amdgcn_mfma_f32_16x16x32_bf16((a), (b), (c), 0, 0, 0)

__device__ __forceinline__ ushort f2b(float x) {
    union { float f; uint32_t u; } c; c.f = x;
    uint32_t u = c.u + 0x7fffu + ((c.u >> 16) & 1u);   // RNE
    return (ushort)(u >> 16);
}

__device__ __forceinline__ void gload_lds16(const ushort* g, ushort* l) {
    __builtin_amdgcn_global_load_lds((const __attribute__((address_space(1))) void*)g,
                                     (__attribute__((address_space(3))) void*)l, 16, 0, 0);
}

__device__ __forceinline__ float gelu_f(float xx) {
    const float a = 0.7978845608f * (xx + 0.044715f * xx * xx * xx);
    const float t2 = 1.0f - 2.0f / (1.0f + __expf(2.0f * a));   // tanh(a)
    return 0.5f * xx * (1.0f + t2);
}

// ---------- 8-wave phase-interleaved GEMM (T3+T4+T5; r13-proven) ----------
// BM x 128 tile, BK=32, 8 waves, 3 LDS buffers. Per K-tile:
//   {counted vmcnt(PER); barrier} then 2 phases, each
//   {ds_read frags || issue stage chunks of tile t+2; barrier; setprio1;
//    MFMA cluster; setprio0; barrier}.
// BM=256: 4Mx2N waves (per-wave 64x64), PER=3. BM=128: 2Mx4N (64x32), PER=2.
// Staging/read lane maps are the r7-proven conflict-free XOR chunks.
template<int BM, int OUTBF, int RES, int GELU>
__global__ __launch_bounds__(512)
void gemm8p(const ushort* __restrict__ A, const ushort* __restrict__ W,
            const float* __restrict__ bias, const float* resid, void* outp,
            int M, int N, int K, int gx)
{
    constexpr int NCA = BM / 16;            // A chunks per K-tile (16 or 8)
    constexpr int NCB = 8;                  // B chunks (BN=128)
    constexpr int PER = (NCA + NCB) / 8;    // loads per wave per K-tile (3 or 2)
    constexpr int WM  = (BM == 256) ? 4 : 2;
    constexpr int WN  = 8 / WM;
    constexpr int NI  = BM / 16 / WM;       // 4 in both configs
    constexpr int NJ  = 128 / 16 / WN;      // 4 (BM=256) or 2 (BM=128)
    __shared__ __align__(16) ushort Als[3][NCA * 512];
    __shared__ __align__(16) ushort Bls[3][NCB * 512];

    const int tid  = threadIdx.x;
    const int lane = tid & 63, wid = tid >> 6;          // 8 waves

    // bijective XCD-aware swizzle (m204)
    const int nwg  = gridDim.x;
    const int orig = blockIdx.x;
    const int xcd = orig & 7, local = orig >> 3;
    const int q8 = nwg >> 3, r8 = nwg & 7;
    const int swz = (xcd < r8 ? xcd * (q8 + 1) : r8 * (q8 + 1) + (xcd - r8) * q8) + local;
    const int bx = swz % gx, by = swz / gx;

    const int m0 = by * BM, n0 = bx * 128;
    const int wr = wid / WN, wc = wid % WN;
    const int ecol = lane & 15, eg = lane >> 4;

    // r7-proven staging map: lane l -> slot l; fetch (row,kc) = dec of swizzle
    const int dec  = lane ^ ((lane >> 3) & 7);
    const int srow = dec >> 2;
    const int scol = (dec & 3) * 8;
    const int sfrag = ecol * 4 + eg;
    const int swslot = sfrag ^ ((sfrag >> 3) & 7);

    f32x4 acc[NI][NJ] = {};

    // chunks: A q=0..NCA-1 (rows q*16), B q=NCA..NCA+7. Wave w owns
    // q = w*PER .. w*PER+PER-1; staged cbeg..cend per phase.
    auto stage = [&](int p, int k0, int cbeg, int cend) {
        for (int c = cbeg; c <= cend; ++c) {
            const int q = wid * PER + c;
            if (q < NCA) {
                int ga = m0 + q * 16 + srow; if (ga > M - 1) ga = M - 1;   // clamp
                gload_lds16(A + (size_t)ga * K + k0 + scol, &Als[p][q * 512]);
            } else {
                const int rg = q - NCA;
                gload_lds16(W + (size_t)(n0 + rg * 16 + srow) * K + k0 + scol,
                            &Bls[p][rg * 512]);
            }
        }
    };

    const int NT = K >> 5;                 // BK=32
    stage(0, 0, 0, PER - 1);
    stage(1, 32, 0, PER - 1);

    for (int t = 0; t < NT; ++t) {
        if (t + 1 < NT) asm volatile("s_waitcnt vmcnt(%0)" :: "n"(PER) : "memory");
        else            asm volatile("s_waitcnt vmcnt(0)" ::: "memory");
        __builtin_amdgcn_s_barrier();
        const int cur = t % 3;
        const int nxt = (t + 2) % 3;
        const int k2  = (t + 2) << 5;
        const bool st = (t + 2) < NT;
#pragma unroll
        for (int ph = 0; ph < 2; ++ph) {
            const int i0 = ph * (NI / 2);
            bf16x8 af[NI / 2], bfr[NJ];
#pragma unroll
            for (int i = 0; i < NI / 2; ++i)
                af[i] = *(const bf16x8*)&Als[cur][(wr * NI + i0 + i) * 512 + swslot * 8];
#pragma unroll
            for (int j = 0; j < NJ; ++j)
                bfr[j] = *(const bf16x8*)&Bls[cur][(wc * NJ + j) * 512 + swslot * 8];
            if (st) {
                if (ph == 0) stage(nxt, k2, 0, PER == 3 ? 1 : 0);
                else         stage(nxt, k2, PER == 3 ? 2 : 1, PER - 1);
            }
            __builtin_amdgcn_s_barrier();
            __builtin_amdgcn_s_setprio(1);
#pragma unroll
            for (int i = 0; i < NI / 2; ++i)
#pragma unroll
                for (int j = 0; j < NJ; ++j)
                    acc[i0 + i][j] = MFMA16(af[i], bfr[j], acc[i0 + i][j]);
            __builtin_amdgcn_s_setprio(0);
            if (ph == 0) __builtin_amdgcn_s_barrier();
        }
    }

#pragma unroll
    for (int i = 0; i < NI; ++i) {
        const int mb = m0 + wr * (NI * 16) + i * 16 + eg * 4;
#pragma unroll
        for (int j = 0; j < NJ; ++j) {
            const int n = n0 + wc * (NJ * 16) + j * 16 + ecol;
            const float bv = bias[n];
#pragma unroll
            for (int r = 0; r < 4; ++r) {
                const int m = mb + r;
                if (m < M) {
                    float v = acc[i][j][r] + bv;
                    if (RES)  v += resid[(size_t)m * N + n];
                    if (GELU) v = gelu_f(v);
                    if (OUTBF) ((ushort*)outp)[(size_t)m * N + n] = f2b(v);
                    else       ((float*)outp)[(size_t)m * N + n]  = v;
                }
            }
        }
    }
}

// ---------- 4-wave 2-phase GEMM (r10-proven; patch embed + proj) ----------
template<int BM, int BN, int OUTBF, int RES, int GELU>
__global__ __launch_bounds__(256)
void gemm_bt(const ushort* __restrict__ A, const ushort* __restrict__ W,
             const float* __restrict__ bias, const float* resid,
             void* outp, int M, int N, int K, int gx)
{
    constexpr int NI   = BM / 32;
    constexpr int NJ   = BN / 32;
    constexpr int NCHA = BM / 16;
    constexpr int NCHB = BN / 16;
    constexpr int NCH  = 2 * (NCHA + NCHB);
    constexpr int PER  = NCH / 4;
    __shared__ __align__(16) ushort Als[2][2 * NCHA * 512];
    __shared__ __align__(16) ushort Bls[2][2 * NCHB * 512];

    const int tid  = threadIdx.x;
    const int lane = tid & 63, wid = tid >> 6;

    const int nwg  = gridDim.x;
    const int orig = blockIdx.x;
    const int xcd = orig & 7, local = orig >> 3;
    const int q8 = nwg >> 3, r8 = nwg & 7;
    const int swz = (xcd < r8 ? xcd * (q8 + 1) : r8 * (q8 + 1) + (xcd - r8) * q8) + local;
    const int bx = swz % gx, by = swz / gx;

    const int m0 = by * BM, n0 = bx * BN;
    const int wr = wid >> 1, wc = wid & 1;
    const int ecol = lane & 15, eg = lane >> 4;

    const int dec  = lane ^ ((lane >> 3) & 7);
    const int srow = dec >> 2;
    const int scol = (dec & 3) * 8;
    const int sfrag = ecol * 4 + eg;
    const int swslot = sfrag ^ ((sfrag >> 3) & 7);

    f32x4 acc[NI][NJ] = {};

    auto stage = [&](int p, int k0) {
#pragma unroll
        for (int c = 0; c < PER; ++c) {
            const int q = wid * PER + c;
            if (q < 2 * NCHA) {
                const int rg = q >> 1, kh = q & 1;
                int ga = m0 + rg * 16 + srow; if (ga > M - 1) ga = M - 1;
                gload_lds16(A + (size_t)ga * K + k0 + kh * 32 + scol, &Als[p][q * 512]);
            } else {
                const int qq = q - 2 * NCHA;
                const int rg = qq >> 1, kh = qq & 1;
                gload_lds16(W + (size_t)(n0 + rg * 16 + srow) * K + k0 + kh * 32 + scol,
                            &Bls[p][qq * 512]);
            }
        }
    };

    const int NT = K >> 6;
    stage(0, 0);
    __syncthreads();

    int cur = 0;
    for (int t = 0; t < NT; ++t) {
        if (t + 1 < NT) stage(cur ^ 1, (t + 1) << 6);
#pragma unroll
        for (int kk = 0; kk < 2; ++kk) {
            bf16x8 af[NI], bfr[NJ];
#pragma unroll
            for (int i = 0; i < NI; ++i)
                af[i] = *(const bf16x8*)&Als[cur][(((wr * NI + i) << 1) + kk) * 512 + swslot * 8];
#pragma unroll
            for (int j = 0; j < NJ; ++j)
                bfr[j] = *(const bf16x8*)&Bls[cur][(((wc * NJ + j) << 1) + kk) * 512 + swslot * 8];
#pragma unroll
            for (int i = 0; i < NI; ++i)
#pragma unroll
                for (int j = 0; j < NJ; ++j)
                    acc[i][j] = MFMA16(af[i], bfr[j], acc[i][j]);
        }
        if (t + 1 < NT) __syncthreads();
        cur ^= 1;
    }

#pragma unroll
    for (int i = 0; i < NI; ++i) {
        const int mb = m0 + wr * (BM / 2) + i * 16 + eg * 4;
#pragma unroll
        for (int j = 0; j < NJ; ++j) {
            const int n = n0 + wc * (BN / 2) + j * 16 + ecol;
            const float bv = bias[n];
#pragma unroll
            for (int r = 0; r < 4; ++r) {
                const int m = mb + r;
                if (m < M) {
                    float v = acc[i][j][r] + bv;
                    if (RES)  v += resid[(size_t)m * N + n];
                    if (GELU) v = gelu_f(v);
                    if (OUTBF) ((ushort*)outp)[(size_t)m * N + n] = f2b(v);
                    else       ((float*)outp)[(size_t)m * N + n]  = v;
                }
            }
        }
    }
}

// ---------- attention: one block per (b, head), 4 waves, q-tiles of 16 ----------
__global__ __launch_bounds__(256)
void attn_k(const ushort* __restrict__ qkv, ushort* __restrict__ o)
{
    __shared__ __align__(16) ushort Vt[64][224];
    __shared__ __align__(16) ushort Pb[4][16][224];
    const int bh = blockIdx.x;
    const int b = bh / 12, hh = bh % 12;
    const int tid = threadIdx.x, lane = tid & 63, wid = tid >> 6;
    const size_t rs = 2304;
    const ushort* qb = qkv + (size_t)b * 197 * rs + hh * 64;
    const ushort* kb = qb + 768;
    const ushort* vb = qb + 1536;

    for (int i = tid; i < 197 * 64; i += 256) {
        const int s = i >> 6, d = i & 63;
        Vt[d][s] = vb[(size_t)s * rs + d];
    }
    for (int i = tid; i < 64 * 27; i += 256) {
        const int d = i / 27, s = 197 + i % 27;
        Vt[d][s] = 0;
    }
    __syncthreads();

    const int ecol = lane & 15, eg = lane >> 4;
    const bool m12bad = (192 + ecol) > 196;

    for (int qt = wid; qt < 13; qt += 4) {
        int qrow = qt * 16 + ecol; if (qrow > 196) qrow = 196;
        bf16x8 qa0 = *(const bf16x8*)&qb[(size_t)qrow * rs + eg * 8];
        bf16x8 qa1 = *(const bf16x8*)&qb[(size_t)qrow * rs + 32 + eg * 8];

        f32x4 s[13];
#pragma unroll
        for (int kt = 0; kt < 13; ++kt) {
            int krow = kt * 16 + ecol; if (krow > 196) krow = 196;
            bf16x8 kf0 = *(const bf16x8*)&kb[(size_t)krow * rs + eg * 8];
            bf16x8 kf1 = *(const bf16x8*)&kb[(size_t)krow * rs + 32 + eg * 8];
            f32x4 a = {};
            a = MFMA16(qa0, kf0, a);
            a = MFMA16(qa1, kf1, a);
            s[kt] = a;
        }
#pragma unroll
        for (int kt = 0; kt < 13; ++kt)
#pragma unroll
            for (int r = 0; r < 4; ++r) s[kt][r] *= 0.125f;
        if (m12bad) { s[12][0] = -1e30f; s[12][1] = -1e30f; s[12][2] = -1e30f; s[12][3] = -1e30f; }

#pragma unroll
        for (int r = 0; r < 4; ++r) {
            float mx = s[0][r];
#pragma unroll
            for (int kt = 1; kt < 13; ++kt) mx = fmaxf(mx, s[kt][r]);
#pragma unroll
            for (int off = 1; off < 16; off <<= 1) mx = fmaxf(mx, __shfl_xor(mx, off));
            float sm = 0.0f;
#pragma unroll
            for (int kt = 0; kt < 13; ++kt) { float e = __expf(s[kt][r] - mx); s[kt][r] = e; sm += e; }
#pragma unroll
            for (int off = 1; off < 16; off <<= 1) sm += __shfl_xor(sm, off);
            const float inv = 1.0f / sm;
#pragma unroll
            for (int kt = 0; kt < 13; ++kt) s[kt][r] *= inv;
        }

#pragma unroll
        for (int kt = 0; kt < 13; ++kt)
#pragma unroll
            for (int r = 0; r < 4; ++r)
                Pb[wid][eg * 4 + r][kt * 16 + ecol] = f2b(s[kt][r]);
#pragma unroll
        for (int r = 0; r < 4; ++r) Pb[wid][eg * 4 + r][208 + ecol] = 0;
        asm volatile("s_waitcnt lgkmcnt(0)" ::: "memory");
        __builtin_amdgcn_sched_barrier(0);

        f32x4 oacc[4] = {};
#pragma unroll
        for (int ks = 0; ks < 7; ++ks) {
            bf16x8 pa = *(const bf16x8*)&Pb[wid][ecol][ks * 32 + eg * 8];
#pragma unroll
            for (int dt = 0; dt < 4; ++dt) {
                bf16x8 vf = *(const bf16x8*)&Vt[dt * 16 + ecol][ks * 32 + eg * 8];
                oacc[dt] = MFMA16(pa, vf, oacc[dt]);
            }
        }
#pragma unroll
        for (int dt = 0; dt < 4; ++dt)
#pragma unroll
            for (int r = 0; r < 4; ++r) {
                const int q = qt * 16 + eg * 4 + r;
                if (q < 197)
                    o[((size_t)(b * 197 + q)) * 768 + hh * 64 + dt * 16 + ecol] = f2b(oacc[dt][r]);
            }
        asm volatile("s_waitcnt lgkmcnt(0)" ::: "memory");
        __builtin_amdgcn_sched_barrier(0);
    }
}

// ---------- LayerNorm (f32 in, bf16 out), one wave per row of 768 ----------
__global__ __launch_bounds__(256)
void ln_k(const float* __restrict__ x, const float* __restrict__ g,
          const float* __restrict__ bta, ushort* __restrict__ y, int rows)
{
    const int row  = blockIdx.x * 4 + (threadIdx.x >> 6);
    const int lane = threadIdx.x & 63;
    if (row >= rows) return;
    const float* xr = x + (size_t)row * 768;
    f32x4 v[3];
#pragma unroll
    for (int t = 0; t < 3; ++t) v[t] = *(const f32x4*)&xr[(lane + t * 64) * 4];
    float s = 0.0f;
#pragma unroll
    for (int t = 0; t < 3; ++t) s += v[t][0] + v[t][1] + v[t][2] + v[t][3];
#pragma unroll
    for (int off = 1; off < 64; off <<= 1) s += __shfl_xor(s, off);
    const float mean = s * (1.0f / 768.0f);
    float sq = 0.0f;
#pragma unroll
    for (int t = 0; t < 3; ++t)
#pragma unroll
        for (int c = 0; c < 4; ++c) { const float d = v[t][c] - mean; sq += d * d; }
#pragma unroll
    for (int off = 1; off < 64; off <<= 1) sq += __shfl_xor(sq, off);
    const float rstd = rsqrtf(sq * (1.0f / 768.0f) + 1e-5f);
    ushort* yr = y + (size_t)row * 768;
#pragma unroll
    for (int t = 0; t < 3; ++t) {
        const int c0 = (lane + t * 64) * 4;
        f32x4 gw = *(const f32x4*)&g[c0];
        f32x4 bb = *(const f32x4*)&bta[c0];
        u16x4 ov;
#pragma unroll
        for (int c = 0; c < 4; ++c) ov[c] = f2b((v[t][c] - mean) * rstd * gw[c] + bb[c]);
        *(u16x4*)&yr[c0] = ov;
    }
}

// ---------- im2col: x f32 -> patches bf16 [6272][768] ----------
__global__ void im2col_k(const float* __restrict__ x, ushort* __restrict__ p)
{
    const int gid = blockIdx.x * 256 + threadIdx.x;
    if (gid >= 6272 * 768) return;
    const int m = gid / 768, idx = gid - m * 768;
    const int b = m / 196, t = m - b * 196;
    const int gy = t / 14, gx = t - gy * 14;
    const int c = idx >> 8, rr = idx & 255;
    const int py = rr >> 4, px = rr & 15;
    const float v = x[(((size_t)(b * 3 + c) * 224) + gy * 16 + py) * 224 + gx * 16 + px];
    p[gid] = f2b(v);
}

// ---------- assemble: h = concat(cls, emb) + pos (all f32) ----------
__global__ void assemble_k(const float* __restrict__ emb, const float* __restrict__ cls,
                           const float* __restrict__ pos, float* __restrict__ h)
{
    const int gid = blockIdx.x * 256 + threadIdx.x;
    if (gid >= 6304 * 192) return;
    const int r = gid / 192, c4 = gid - r * 192;
    const int b = r / 197, s = r - b * 197;
    f32x4 pe = *(const f32x4*)&pos[(s * 192 + c4) * 4];
    f32x4 sv;
    if (s == 0) sv = *(const f32x4*)&cls[c4 * 4];
    else        sv = *(const f32x4*)&emb[((size_t)(b * 196 + (s - 1)) * 192 + c4) * 4];
    f32x4 ov = pe + sv;
    *(f32x4*)&h[(size_t)gid * 4] = ov;
}

// ---------- generic f32 -> bf16 convert (8 elems/thread) ----------
__global__ void cvt_k(const float* __restrict__ src, ushort* __restrict__ dst, int n8)
{
    const int g = blockIdx.x * 256 + threadIdx.x;
    if (g >= n8) return;
    const int e = g * 8;
    f32x4 a = *(const f32x4*)&src[e];
    f32x4 b = *(const f32x4*)&src[e + 4];
    u16x8 ov;
#pragma unroll
    for (int c = 0; c < 4; ++c) { ov[c] = f2b(a[c]); ov[4 + c] = f2b(b[c]); }
    *(u16x8*)&dst[e] = ov;
}

// ---------- fused per-layer weight convert + qkv-bias concat ----------
__global__ void conv6_k(const float* __restrict__ s0, const float* __restrict__ s1,
                        const float* __restrict__ s2, const float* __restrict__ s3,
                        const float* __restrict__ s4, const float* __restrict__ s5,
                        ushort* __restrict__ dst,
                        const float* __restrict__ bq, const float* __restrict__ bk,
                        const float* __restrict__ bv, float* __restrict__ b3)
{
    const int g = blockIdx.x * 256 + threadIdx.x;
    if (g >= 884736) {                       // bias-concat tail (2304 elems)
        const int i = g - 884736;
        if (i < 2304)
            b3[i] = (i < 768) ? bq[i] : (i < 1536 ? bk[i - 768] : bv[i - 1536]);
        return;
    }
    const int e = g * 8;
    const float* src; int off;
    if      (e < 589824)  { src = s0; off = e; }
    else if (e < 1179648) { src = s1; off = e - 589824; }
    else if (e < 1769472) { src = s2; off = e - 1179648; }
    else if (e < 2359296) { src = s3; off = e - 1769472; }
    else if (e < 4718592) { src = s4; off = e - 2359296; }
    else                  { src = s5; off = e - 4718592; }
    f32x4 a = *(const f32x4*)&src[off];
    f32x4 b = *(const f32x4*)&src[off + 4];
    u16x8 ov;
#pragma unroll
    for (int c = 0; c < 4; ++c) { ov[c] = f2b(a[c]); ov[4 + c] = f2b(b[c]); }
    *(u16x8*)&dst[e] = ov;
}

// ---------- classifier: logits[b,n] from h[b*197] row, f32 out ----------
__global__ __launch_bounds__(64)
void clf_k(const float* __restrict__ h, const float* __restrict__ w,
           const float* __restrict__ bias, float* __restrict__ out)
{
    const int b = blockIdx.x, lane = threadIdx.x;
    const float* hr = h + (size_t)b * 197 * 768;
    float hv[12];
#pragma unroll
    for (int j = 0; j < 12; ++j) hv[j] = hr[lane + j * 64];
    for (int n = 0; n < 14; ++n) {
        float sm = 0.0f;
#pragma unroll
        for (int j = 0; j < 12; ++j) sm += hv[j] * w[n * 768 + lane + j * 64];
#pragma unroll
        for (int off = 1; off < 64; off <<= 1) sm += __shfl_xor(sm, off);
        if (lane == 0) out[b * 14 + n] = sm + bias[n];
    }
}

// ---------- launcher ----------
extern "C" void kernel_launch(void* const* d_in, const int* in_sizes, int n_in,
                              void* d_out, int out_size, void* d_ws, size_t ws_size,
                              hipStream_t stream)
{
    const float* x       = (const float*)d_in[0];
    const float* patch_w = (const float*)d_in[1];
    const float* patch_b = (const float*)d_in[2];
    const float* cls_tok = (const float*)d_in[3];
    const float* pos_emb = (const float*)d_in[4];
    const float* ln1_w   = (const float*)d_in[5];
    const float* ln1_b   = (const float*)d_in[6];
    const float* wq      = (const float*)d_in[7];
    const float* bq      = (const float*)d_in[8];
    const float* wk      = (const float*)d_in[9];
    const float* bk      = (const float*)d_in[10];
    const float* wv      = (const float*)d_in[11];
    const float* bv      = (const float*)d_in[12];
    const float* wo      = (const float*)d_in[13];
    const float* bo      = (const float*)d_in[14];
    const float* ln2_w   = (const float*)d_in[15];
    const float* ln2_b   = (const float*)d_in[16];
    const float* fc1w    = (const float*)d_in[17];
    const float* fc1b    = (const float*)d_in[18];
    const float* fc2w    = (const float*)d_in[19];
    const float* fc2b    = (const float*)d_in[20];
    const float* clfw    = (const float*)d_in[21];
    const float* clfb    = (const float*)d_in[22];

    char* ws = (char*)d_ws;
    float*  h    = (float*)(ws + 0);                    // 6304*768 f32
    ushort* y    = (ushort*)(ws + 19365888);            // 6304*768 bf16
    ushort* qkv  = (ushort*)(ws + 29048832);            // 6304*2304 bf16
    ushort* o    = (ushort*)(ws + 58097664);            // 6304*768 bf16
    ushort* ff   = (ushort*)(ws + 67780608);            // 6304*3072 bf16
    ushort* wbuf = (ushort*)(ws + 106512384);           // 7,077,888 bf16 (per-layer)
    float*  b3   = (float*)(ws + 120668160);            // 2304 f32
    ushort* patches = (ushort*)(ws + 67780608);         // alias ff (used pre-loop)
    float*  emb     = (float*)(ws + 67780608 + 16777216); // alias ff+16MB

    // patch embed
    im2col_k<<<18816, 256, 0, stream>>>(x, patches);
    cvt_k<<<288, 256, 0, stream>>>(patch_w, wbuf, 73728);
    gemm_bt<128, 64, 0, 0, 0><<<12 * 49, 256, 0, stream>>>(patches, wbuf, patch_b,
                                                      (const float*)nullptr, (void*)emb, 6272, 768, 768, 12);
    assemble_k<<<4728, 256, 0, stream>>>(emb, cls_tok, pos_emb, h);

    for (int l = 0; l < 12; ++l) {
        conv6_k<<<3466, 256, 0, stream>>>(wq + (size_t)l * 589824, wk + (size_t)l * 589824,
                                          wv + (size_t)l * 589824, wo + (size_t)l * 589824,
                                          fc1w + (size_t)l * 2359296, fc2w + (size_t)l * 2359296, wbuf,
                                          bq + l * 768, bk + l * 768, bv + l * 768, b3);
        ln_k<<<1576, 256, 0, stream>>>(h, ln1_w + l * 768, ln1_b + l * 768, y, 6304);
        gemm8p<256, 1, 0, 0><<<18 * 25, 512, 0, stream>>>(y, wbuf, b3,
                                                          (const float*)nullptr, (void*)qkv, 6304, 2304, 768, 18);
        attn_k<<<384, 256, 0, stream>>>(qkv, o);
        gemm_bt<128, 64, 0, 1, 0><<<12 * 50, 256, 0, stream>>>(o, wbuf + 1769472, bo + l * 768,
                                                          (const float*)h, (void*)h, 6304, 768, 768, 12);
        ln_k<<<1576, 256, 0, stream>>>(h, ln2_w + l * 768, ln2_b + l * 768, y, 6304);
        gemm8p<256, 1, 0, 1><<<24 * 25, 512, 0, stream>>>(y, wbuf + 2359296, fc1b + (size_t)l * 3072,
                                                          (const float*)nullptr, (void*)ff, 6304, 3072, 768, 24);
        gemm8p<128, 0, 1, 0><<<6 * 50, 512, 0, stream>>>(ff, wbuf + 4718592, fc2b + l * 768,
                                                         (const float*)h, (void*)h, 6304, 768, 3072, 6);
    }
    clf_k<<<32, 64, 0, stream>>>(h, clfw, clfb, (float*)d_out);
}

// Round 16
// 2997.328 us; speedup vs baseline: 1.0464x; 1.0324x over previous
//
#include <hip/hip_runtime.h>
#include <hip/hip_bf16.h>
#include <cstdint>
#include <cstddef>

// ---------- types ----------
typedef __attribute__((ext_vector_type(8))) short  bf16x8;
typedef __attribute__((ext_vector_type(4))) float  f32x4;
typedef __attribute__((ext_vector_type(4))) ushort u16x4;
typedef __attribute__((ext_vector_type(8))) ushort u16x8;

#define MFMA16(a, b, c) __builtin_amdgcn_mfma_f32_16x16x32_bf16((a), (b), (c), 0, 0, 0)

__device__ __forceinline__ ushort f2b(float x) {
    union { float f; uint32_t u; } c; c.f = x;
    uint32_t u = c.u + 0x7fffu + ((c.u >> 16) & 1u);   // RNE
    return (ushort)(u >> 16);
}

__device__ __forceinline__ void gload_lds16(const ushort* g, ushort* l) {
    __builtin_amdgcn_global_load_lds((const __attribute__((address_space(1))) void*)g,
                                     (__attribute__((address_space(3))) void*)l, 16, 0, 0);
}

__device__ __forceinline__ float gelu_f(float xx) {
    const float a = 0.7978845608f * (xx + 0.044715f * xx * xx * xx);
    const float t2 = 1.0f - 2.0f / (1.0f + __expf(2.0f * a));   // tanh(a)
    return 0.5f * xx * (1.0f + t2);
}

// ---------- 8-wave GEMM, 3-buffer depth-2, counted vmcnt, ONE barrier/K-tile ----
// BM x 128 tile, BK=32, 8 waves. Per K-tile:
//   {counted vmcnt(PER); s_barrier} -> stage all PER chunks of tile t+2 ->
//   ds_read frags -> setprio1 -> 16/8-MFMA cluster -> setprio0.
// (r13 had 2 extra intra-phase barriers; audit shows only the boundary barrier
//  is needed for correctness — stage(t+2) hits buf (t-1)%3 whose readers
//  finished lgkm-fenced ds_reads before the boundary.)
// BM=256: 4Mx2N waves (per-wave 64x64), PER=3. BM=128: 2Mx4N (64x32), PER=2.
// Staging/read lane maps: r7-proven conflict-free XOR chunks.
template<int BM, int OUTBF, int RES, int GELU>
__global__ __launch_bounds__(512)
void gemm8p(const ushort* __restrict__ A, const ushort* __restrict__ W,
            const float* __restrict__ bias, const float* resid, void* outp,
            int M, int N, int K, int gx)
{
    constexpr int NCA = BM / 16;            // A chunks per K-tile (16 or 8)
    constexpr int NCB = 8;                  // B chunks (BN=128)
    constexpr int PER = (NCA + NCB) / 8;    // loads per wave per K-tile (3 or 2)
    constexpr int WM  = (BM == 256) ? 4 : 2;
    constexpr int WN  = 8 / WM;
    constexpr int NI  = BM / 16 / WM;       // 4 in both configs
    constexpr int NJ  = 128 / 16 / WN;      // 4 (BM=256) or 2 (BM=128)
    __shared__ __align__(16) ushort Als[3][NCA * 512];
    __shared__ __align__(16) ushort Bls[3][NCB * 512];

    const int tid  = threadIdx.x;
    const int lane = tid & 63, wid = tid >> 6;          // 8 waves

    // bijective XCD-aware swizzle (m204)
    const int nwg  = gridDim.x;
    const int orig = blockIdx.x;
    const int xcd = orig & 7, local = orig >> 3;
    const int q8 = nwg >> 3, r8 = nwg & 7;
    const int swz = (xcd < r8 ? xcd * (q8 + 1) : r8 * (q8 + 1) + (xcd - r8) * q8) + local;
    const int bx = swz % gx, by = swz / gx;

    const int m0 = by * BM, n0 = bx * 128;
    const int wr = wid / WN, wc = wid % WN;
    const int ecol = lane & 15, eg = lane >> 4;

    // r7-proven staging map: lane l -> slot l; fetch (row,kc) = dec of swizzle
    const int dec  = lane ^ ((lane >> 3) & 7);
    const int srow = dec >> 2;
    const int scol = (dec & 3) * 8;
    const int sfrag = ecol * 4 + eg;
    const int swslot = sfrag ^ ((sfrag >> 3) & 7);

    f32x4 acc[NI][NJ] = {};

    // chunks: A q=0..NCA-1 (rows q*16), B q=NCA..NCA+7. Wave w owns
    // q = w*PER .. w*PER+PER-1.
    auto stage = [&](int p, int k0) {
#pragma unroll
        for (int c = 0; c < PER; ++c) {
            const int q = wid * PER + c;
            if (q < NCA) {
                int ga = m0 + q * 16 + srow; if (ga > M - 1) ga = M - 1;   // clamp
                gload_lds16(A + (size_t)ga * K + k0 + scol, &Als[p][q * 512]);
            } else {
                const int rg = q - NCA;
                gload_lds16(W + (size_t)(n0 + rg * 16 + srow) * K + k0 + scol,
                            &Bls[p][rg * 512]);
            }
        }
    };

    const int NT = K >> 5;                 // BK=32
    stage(0, 0);
    stage(1, 32);

    for (int t = 0; t < NT; ++t) {
        if (t + 1 < NT) asm volatile("s_waitcnt vmcnt(%0)" :: "n"(PER) : "memory");
        else            asm volatile("s_waitcnt vmcnt(0)" ::: "memory");
        __builtin_amdgcn_s_barrier();
        const int cur = t % 3;
        if (t + 2 < NT) stage((t + 2) % 3, (t + 2) << 5);   // buf of t-1: readers done
        bf16x8 af[NI], bfr[NJ];
#pragma unroll
        for (int i = 0; i < NI; ++i)
            af[i] = *(const bf16x8*)&Als[cur][(wr * NI + i) * 512 + swslot * 8];
#pragma unroll
        for (int j = 0; j < NJ; ++j)
            bfr[j] = *(const bf16x8*)&Bls[cur][(wc * NJ + j) * 512 + swslot * 8];
        __builtin_amdgcn_s_setprio(1);
#pragma unroll
        for (int i = 0; i < NI; ++i)
#pragma unroll
            for (int j = 0; j < NJ; ++j)
                acc[i][j] = MFMA16(af[i], bfr[j], acc[i][j]);
        __builtin_amdgcn_s_setprio(0);
    }

#pragma unroll
    for (int i = 0; i < NI; ++i) {
        const int mb = m0 + wr * (NI * 16) + i * 16 + eg * 4;
#pragma unroll
        for (int j = 0; j < NJ; ++j) {
            const int n = n0 + wc * (NJ * 16) + j * 16 + ecol;
            const float bv = bias[n];
#pragma unroll
            for (int r = 0; r < 4; ++r) {
                const int m = mb + r;
                if (m < M) {
                    float v = acc[i][j][r] + bv;
                    if (RES)  v += resid[(size_t)m * N + n];
                    if (GELU) v = gelu_f(v);
                    if (OUTBF) ((ushort*)outp)[(size_t)m * N + n] = f2b(v);
                    else       ((float*)outp)[(size_t)m * N + n]  = v;
                }
            }
        }
    }
}

// ---------- 4-wave 2-phase GEMM (r10-proven; patch embed + proj) ----------
template<int BM, int BN, int OUTBF, int RES, int GELU>
__global__ __launch_bounds__(256)
void gemm_bt(const ushort* __restrict__ A, const ushort* __restrict__ W,
             const float* __restrict__ bias, const float* resid,
             void* outp, int M, int N, int K, int gx)
{
    constexpr int NI   = BM / 32;
    constexpr int NJ   = BN / 32;
    constexpr int NCHA = BM / 16;
    constexpr int NCHB = BN / 16;
    constexpr int NCH  = 2 * (NCHA + NCHB);
    constexpr int PER  = NCH / 4;
    __shared__ __align__(16) ushort Als[2][2 * NCHA * 512];
    __shared__ __align__(16) ushort Bls[2][2 * NCHB * 512];

    const int tid  = threadIdx.x;
    const int lane = tid & 63, wid = tid >> 6;

    const int nwg  = gridDim.x;
    const int orig = blockIdx.x;
    const int xcd = orig & 7, local = orig >> 3;
    const int q8 = nwg >> 3, r8 = nwg & 7;
    const int swz = (xcd < r8 ? xcd * (q8 + 1) : r8 * (q8 + 1) + (xcd - r8) * q8) + local;
    const int bx = swz % gx, by = swz / gx;

    const int m0 = by * BM, n0 = bx * BN;
    const int wr = wid >> 1, wc = wid & 1;
    const int ecol = lane & 15, eg = lane >> 4;

    const int dec  = lane ^ ((lane >> 3) & 7);
    const int srow = dec >> 2;
    const int scol = (dec & 3) * 8;
    const int sfrag = ecol * 4 + eg;
    const int swslot = sfrag ^ ((sfrag >> 3) & 7);

    f32x4 acc[NI][NJ] = {};

    auto stage = [&](int p, int k0) {
#pragma unroll
        for (int c = 0; c < PER; ++c) {
            const int q = wid * PER + c;
            if (q < 2 * NCHA) {
                const int rg = q >> 1, kh = q & 1;
                int ga = m0 + rg * 16 + srow; if (ga > M - 1) ga = M - 1;
                gload_lds16(A + (size_t)ga * K + k0 + kh * 32 + scol, &Als[p][q * 512]);
            } else {
                const int qq = q - 2 * NCHA;
                const int rg = qq >> 1, kh = qq & 1;
                gload_lds16(W + (size_t)(n0 + rg * 16 + srow) * K + k0 + kh * 32 + scol,
                            &Bls[p][qq * 512]);
            }
        }
    };

    const int NT = K >> 6;
    stage(0, 0);
    __syncthreads();

    int cur = 0;
    for (int t = 0; t < NT; ++t) {
        if (t + 1 < NT) stage(cur ^ 1, (t + 1) << 6);
#pragma unroll
        for (int kk = 0; kk < 2; ++kk) {
            bf16x8 af[NI], bfr[NJ];
#pragma unroll
            for (int i = 0; i < NI; ++i)
                af[i] = *(const bf16x8*)&Als[cur][(((wr * NI + i) << 1) + kk) * 512 + swslot * 8];
#pragma unroll
            for (int j = 0; j < NJ; ++j)
                bfr[j] = *(const bf16x8*)&Bls[cur][(((wc * NJ + j) << 1) + kk) * 512 + swslot * 8];
#pragma unroll
            for (int i = 0; i < NI; ++i)
#pragma unroll
                for (int j = 0; j < NJ; ++j)
                    acc[i][j] = MFMA16(af[i], bfr[j], acc[i][j]);
        }
        if (t + 1 < NT) __syncthreads();
        cur ^= 1;
    }

#pragma unroll
    for (int i = 0; i < NI; ++i) {
        const int mb = m0 + wr * (BM / 2) + i * 16 + eg * 4;
#pragma unroll
        for (int j = 0; j < NJ; ++j) {
            const int n = n0 + wc * (BN / 2) + j * 16 + ecol;
            const float bv = bias[n];
#pragma unroll
            for (int r = 0; r < 4; ++r) {
                const int m = mb + r;
                if (m < M) {
                    float v = acc[i][j][r] + bv;
                    if (RES)  v += resid[(size_t)m * N + n];
                    if (GELU) v = gelu_f(v);
                    if (OUTBF) ((ushort*)outp)[(size_t)m * N + n] = f2b(v);
                    else       ((float*)outp)[(size_t)m * N + n]  = v;
                }
            }
        }
    }
}

// ---------- attention: one block per (b, head), 4 waves, q-tiles of 16 ----------
__global__ __launch_bounds__(256)
void attn_k(const ushort* __restrict__ qkv, ushort* __restrict__ o)
{
    __shared__ __align__(16) ushort Vt[64][224];
    __shared__ __align__(16) ushort Pb[4][16][224];
    const int bh = blockIdx.x;
    const int b = bh / 12, hh = bh % 12;
    const int tid = threadIdx.x, lane = tid & 63, wid = tid >> 6;
    const size_t rs = 2304;
    const ushort* qb = qkv + (size_t)b * 197 * rs + hh * 64;
    const ushort* kb = qb + 768;
    const ushort* vb = qb + 1536;

    for (int i = tid; i < 197 * 64; i += 256) {
        const int s = i >> 6, d = i & 63;
        Vt[d][s] = vb[(size_t)s * rs + d];
    }
    for (int i = tid; i < 64 * 27; i += 256) {
        const int d = i / 27, s = 197 + i % 27;
        Vt[d][s] = 0;
    }
    __syncthreads();

    const int ecol = lane & 15, eg = lane >> 4;
    const bool m12bad = (192 + ecol) > 196;

    for (int qt = wid; qt < 13; qt += 4) {
        int qrow = qt * 16 + ecol; if (qrow > 196) qrow = 196;
        bf16x8 qa0 = *(const bf16x8*)&qb[(size_t)qrow * rs + eg * 8];
        bf16x8 qa1 = *(const bf16x8*)&qb[(size_t)qrow * rs + 32 + eg * 8];

        f32x4 s[13];
#pragma unroll
        for (int kt = 0; kt < 13; ++kt) {
            int krow = kt * 16 + ecol; if (krow > 196) krow = 196;
            bf16x8 kf0 = *(const bf16x8*)&kb[(size_t)krow * rs + eg * 8];
            bf16x8 kf1 = *(const bf16x8*)&kb[(size_t)krow * rs + 32 + eg * 8];
            f32x4 a = {};
            a = MFMA16(qa0, kf0, a);
            a = MFMA16(qa1, kf1, a);
            s[kt] = a;
        }
#pragma unroll
        for (int kt = 0; kt < 13; ++kt)
#pragma unroll
            for (int r = 0; r < 4; ++r) s[kt][r] *= 0.125f;
        if (m12bad) { s[12][0] = -1e30f; s[12][1] = -1e30f; s[12][2] = -1e30f; s[12][3] = -1e30f; }

#pragma unroll
        for (int r = 0; r < 4; ++r) {
            float mx = s[0][r];
#pragma unroll
            for (int kt = 1; kt < 13; ++kt) mx = fmaxf(mx, s[kt][r]);
#pragma unroll
            for (int off = 1; off < 16; off <<= 1) mx = fmaxf(mx, __shfl_xor(mx, off));
            float sm = 0.0f;
#pragma unroll
            for (int kt = 0; kt < 13; ++kt) { float e = __expf(s[kt][r] - mx); s[kt][r] = e; sm += e; }
#pragma unroll
            for (int off = 1; off < 16; off <<= 1) sm += __shfl_xor(sm, off);
            const float inv = 1.0f / sm;
#pragma unroll
            for (int kt = 0; kt < 13; ++kt) s[kt][r] *= inv;
        }

#pragma unroll
        for (int kt = 0; kt < 13; ++kt)
#pragma unroll
            for (int r = 0; r < 4; ++r)
                Pb[wid][eg * 4 + r][kt * 16 + ecol] = f2b(s[kt][r]);
#pragma unroll
        for (int r = 0; r < 4; ++r) Pb[wid][eg * 4 + r][208 + ecol] = 0;
        asm volatile("s_waitcnt lgkmcnt(0)" ::: "memory");
        __builtin_amdgcn_sched_barrier(0);

        f32x4 oacc[4] = {};
#pragma unroll
        for (int ks = 0; ks < 7; ++ks) {
            bf16x8 pa = *(const bf16x8*)&Pb[wid][ecol][ks * 32 + eg * 8];
#pragma unroll
            for (int dt = 0; dt < 4; ++dt) {
                bf16x8 vf = *(const bf16x8*)&Vt[dt * 16 + ecol][ks * 32 + eg * 8];
                oacc[dt] = MFMA16(pa, vf, oacc[dt]);
            }
        }
#pragma unroll
        for (int dt = 0; dt < 4; ++dt)
#pragma unroll
            for (int r = 0; r < 4; ++r) {
                const int q = qt * 16 + eg * 4 + r;
                if (q < 197)
                    o[((size_t)(b * 197 + q)) * 768 + hh * 64 + dt * 16 + ecol] = f2b(oacc[dt][r]);
            }
        asm volatile("s_waitcnt lgkmcnt(0)" ::: "memory");
        __builtin_amdgcn_sched_barrier(0);
    }
}

// ---------- LayerNorm (f32 in, bf16 out), one wave per row of 768 ----------
__global__ __launch_bounds__(256)
void ln_k(const float* __restrict__ x, const float* __restrict__ g,
          const float* __restrict__ bta, ushort* __restrict__ y, int rows)
{
    const int row  = blockIdx.x * 4 + (threadIdx.x >> 6);
    const int lane = threadIdx.x & 63;
    if (row >= rows) return;
    const float* xr = x + (size_t)row * 768;
    f32x4 v[3];
#pragma unroll
    for (int t = 0; t < 3; ++t) v[t] = *(const f32x4*)&xr[(lane + t * 64) * 4];
    float s = 0.0f;
#pragma unroll
    for (int t = 0; t < 3; ++t) s += v[t][0] + v[t][1] + v[t][2] + v[t][3];
#pragma unroll
    for (int off = 1; off < 64; off <<= 1) s += __shfl_xor(s, off);
    const float mean = s * (1.0f / 768.0f);
    float sq = 0.0f;
#pragma unroll
    for (int t = 0; t < 3; ++t)
#pragma unroll
        for (int c = 0; c < 4; ++c) { const float d = v[t][c] - mean; sq += d * d; }
#pragma unroll
    for (int off = 1; off < 64; off <<= 1) sq += __shfl_xor(sq, off);
    const float rstd = rsqrtf(sq * (1.0f / 768.0f) + 1e-5f);
    ushort* yr = y + (size_t)row * 768;
#pragma unroll
    for (int t = 0; t < 3; ++t) {
        const int c0 = (lane + t * 64) * 4;
        f32x4 gw = *(const f32x4*)&g[c0];
        f32x4 bb = *(const f32x4*)&bta[c0];
        u16x4 ov;
#pragma unroll
        for (int c = 0; c < 4; ++c) ov[c] = f2b((v[t][c] - mean) * rstd * gw[c] + bb[c]);
        *(u16x4*)&yr[c0] = ov;
    }
}

// ---------- im2col: x f32 -> patches bf16 [6272][768] ----------
__global__ void im2col_k(const float* __restrict__ x, ushort* __restrict__ p)
{
    const int gid = blockIdx.x * 256 + threadIdx.x;
    if (gid >= 6272 * 768) return;
    const int m = gid / 768, idx = gid - m * 768;
    const int b = m / 196, t = m - b * 196;
    const int gy = t / 14, gx = t - gy * 14;
    const int c = idx >> 8, rr = idx & 255;
    const int py = rr >> 4, px = rr & 15;
    const float v = x[(((size_t)(b * 3 + c) * 224) + gy * 16 + py) * 224 + gx * 16 + px];
    p[gid] = f2b(v);
}

// ---------- assemble: h = concat(cls, emb) + pos (all f32) ----------
__global__ void assemble_k(const float* __restrict__ emb, const float* __restrict__ cls,
                           const float* __restrict__ pos, float* __restrict__ h)
{
    const int gid = blockIdx.x * 256 + threadIdx.x;
    if (gid >= 6304 * 192) return;
    const int r = gid / 192, c4 = gid - r * 192;
    const int b = r / 197, s = r - b * 197;
    f32x4 pe = *(const f32x4*)&pos[(s * 192 + c4) * 4];
    f32x4 sv;
    if (s == 0) sv = *(const f32x4*)&cls[c4 * 4];
    else        sv = *(const f32x4*)&emb[((size_t)(b * 196 + (s - 1)) * 192 + c4) * 4];
    f32x4 ov = pe + sv;
    *(f32x4*)&h[(size_t)gid * 4] = ov;
}

// ---------- generic f32 -> bf16 convert (8 elems/thread) ----------
__global__ void cvt_k(const float* __restrict__ src, ushort* __restrict__ dst, int n8)
{
    const int g = blockIdx.x * 256 + threadIdx.x;
    if (g >= n8) return;
    const int e = g * 8;
    f32x4 a = *(const f32x4*)&src[e];
    f32x4 b = *(const f32x4*)&src[e + 4];
    u16x8 ov;
#pragma unroll
    for (int c = 0; c < 4; ++c) { ov[c] = f2b(a[c]); ov[4 + c] = f2b(b[c]); }
    *(u16x8*)&dst[e] = ov;
}

// ---------- fused per-layer weight convert + qkv-bias concat ----------
__global__ void conv6_k(const float* __restrict__ s0, const float* __restrict__ s1,
                        const float* __restrict__ s2, const float* __restrict__ s3,
                        const float* __restrict__ s4, const float* __restrict__ s5,
                        ushort* __restrict__ dst,
                        const float* __restrict__ bq, const float* __restrict__ bk,
                        const float* __restrict__ bv, float* __restrict__ b3)
{
    const int g = blockIdx.x * 256 + threadIdx.x;
    if (g >= 884736) {                       // bias-concat tail (2304 elems)
        const int i = g - 884736;
        if (i < 2304)
            b3[i] = (i < 768) ? bq[i] : (i < 1536 ? bk[i - 768] : bv[i - 1536]);
        return;
    }
    const int e = g * 8;
    const float* src; int off;
    if      (e < 589824)  { src = s0; off = e; }
    else if (e < 1179648) { src = s1; off = e - 589824; }
    else if (e < 1769472) { src = s2; off = e - 1179648; }
    else if (e < 2359296) { src = s3; off = e - 1769472; }
    else if (e < 4718592) { src = s4; off = e - 2359296; }
    else                  { src = s5; off = e - 4718592; }
    f32x4 a = *(const f32x4*)&src[off];
    f32x4 b = *(const f32x4*)&src[off + 4];
    u16x8 ov;
#pragma unroll
    for (int c = 0; c < 4; ++c) { ov[c] = f2b(a[c]); ov[4 + c] = f2b(b[c]); }
    *(u16x8*)&dst[e] = ov;
}

// ---------- classifier: logits[b,n] from h[b*197] row, f32 out ----------
__global__ __launch_bounds__(64)
void clf_k(const float* __restrict__ h, const float* __restrict__ w,
           const float* __restrict__ bias, float* __restrict__ out)
{
    const int b = blockIdx.x, lane = threadIdx.x;
    const float* hr = h + (size_t)b * 197 * 768;
    float hv[12];
#pragma unroll
    for (int j = 0; j < 12; ++j) hv[j] = hr[lane + j * 64];
    for (int n = 0; n < 14; ++n) {
        float sm = 0.0f;
#pragma unroll
        for (int j = 0; j < 12; ++j) sm += hv[j] * w[n * 768 + lane + j * 64];
#pragma unroll
        for (int off = 1; off < 64; off <<= 1) sm += __shfl_xor(sm, off);
        if (lane == 0) out[b * 14 + n] = sm + bias[n];
    }
}

// ---------- launcher ----------
extern "C" void kernel_launch(void* const* d_in, const int* in_sizes, int n_in,
                              void* d_out, int out_size, void* d_ws, size_t ws_size,
                              hipStream_t stream)
{
    const float* x       = (const float*)d_in[0];
    const float* patch_w = (const float*)d_in[1];
    const float* patch_b = (const float*)d_in[2];
    const float* cls_tok = (const float*)d_in[3];
    const float* pos_emb = (const float*)d_in[4];
    const float* ln1_w   = (const float*)d_in[5];
    const float* ln1_b   = (const float*)d_in[6];
    const float* wq      = (const float*)d_in[7];
    const float* bq      = (const float*)d_in[8];
    const float* wk      = (const float*)d_in[9];
    const float* bk      = (const float*)d_in[10];
    const float* wv      = (const float*)d_in[11];
    const float* bv      = (const float*)d_in[12];
    const float* wo      = (const float*)d_in[13];
    const float* bo      = (const float*)d_in[14];
    const float* ln2_w   = (const float*)d_in[15];
    const float* ln2_b   = (const float*)d_in[16];
    const float* fc1w    = (const float*)d_in[17];
    const float* fc1b    = (const float*)d_in[18];
    const float* fc2w    = (const float*)d_in[19];
    const float* fc2b    = (const float*)d_in[20];
    const float* clfw    = (const float*)d_in[21];
    const float* clfb    = (const float*)d_in[22];

    char* ws = (char*)d_ws;
    float*  h    = (float*)(ws + 0);                    // 6304*768 f32
    ushort* y    = (ushort*)(ws + 19365888);            // 6304*768 bf16
    ushort* qkv  = (ushort*)(ws + 29048832);            // 6304*2304 bf16
    ushort* o    = (ushort*)(ws + 58097664);            // 6304*768 bf16
    ushort* ff   = (ushort*)(ws + 67780608);            // 6304*3072 bf16
    ushort* wbuf = (ushort*)(ws + 106512384);           // 7,077,888 bf16 (per-layer)
    float*  b3   = (float*)(ws + 120668160);            // 2304 f32
    ushort* patches = (ushort*)(ws + 67780608);         // alias ff (used pre-loop)
    float*  emb     = (float*)(ws + 67780608 + 16777216); // alias ff+16MB

    // patch embed
    im2col_k<<<18816, 256, 0, stream>>>(x, patches);
    cvt_k<<<288, 256, 0, stream>>>(patch_w, wbuf, 73728);
    gemm_bt<128, 64, 0, 0, 0><<<12 * 49, 256, 0, stream>>>(patches, wbuf, patch_b,
                                                      (const float*)nullptr, (void*)emb, 6272, 768, 768, 12);
    assemble_k<<<4728, 256, 0, stream>>>(emb, cls_tok, pos_emb, h);

    for (int l = 0; l < 12; ++l) {
        conv6_k<<<3466, 256, 0, stream>>>(wq + (size_t)l * 589824, wk + (size_t)l * 589824,
                                          wv + (size_t)l * 589824, wo + (size_t)l * 589824,
                                          fc1w + (size_t)l * 2359296, fc2w + (size_t)l * 2359296, wbuf,
                                          bq + l * 768, bk + l * 768, bv + l * 768, b3);
        ln_k<<<1576, 256, 0, stream>>>(h, ln1_w + l * 768, ln1_b + l * 768, y, 6304);
        gemm8p<256, 1, 0, 0><<<18 * 25, 512, 0, stream>>>(y, wbuf, b3,
                                                          (const float*)nullptr, (void*)qkv, 6304, 2304, 768, 18);
        attn_k<<<384, 256, 0, stream>>>(qkv, o);
        gemm_bt<128, 64, 0, 1, 0><<<12 * 50, 256, 0, stream>>>(o, wbuf + 1769472, bo + l * 768,
                                                          (const float*)h, (void*)h, 6304, 768, 768, 12);
        ln_k<<<1576, 256, 0, stream>>>(h, ln2_w + l * 768, ln2_b + l * 768, y, 6304);
        gemm8p<256, 1, 0, 1><<<24 * 25, 512, 0, stream>>>(y, wbuf + 2359296, fc1b + (size_t)l * 3072,
                                                          (const float*)nullptr, (void*)ff, 6304, 3072, 768, 24);
        gemm8p<128, 0, 1, 0><<<6 * 50, 512, 0, stream>>>(ff, wbuf + 4718592, fc2b + l * 768,
                                                         (const float*)h, (void*)h, 6304, 768, 3072, 6);
    }
    clf_k<<<32, 64, 0, stream>>>(h, clfw, clfb, (float*)d_out);
}

// Round 17
// 2942.846 us; speedup vs baseline: 1.0658x; 1.0185x over previous
//
#include <hip/hip_runtime.h>
#include <hip/hip_bf16.h>
#include <cstdint>
#include <cstddef>

// ---------- types ----------
typedef __attribute__((ext_vector_type(8))) short  bf16x8;
typedef __attribute__((ext_vector_type(4))) float  f32x4;
typedef __attribute__((ext_vector_type(4))) ushort u16x4;
typedef __attribute__((ext_vector_type(8))) ushort u16x8;

#define MFMA16(a, b, c) __builtin_amdgcn_mfma_f32_16x16x32_bf16((a), (b), (c), 0, 0, 0)

__device__ __forceinline__ ushort f2b(float x) {
    union { float f; uint32_t u; } c; c.f = x;
    uint32_t u = c.u + 0x7fffu + ((c.u >> 16) & 1u);   // RNE
    return (ushort)(u >> 16);
}

__device__ __forceinline__ void gload_lds16(const ushort* g, ushort* l) {
    __builtin_amdgcn_global_load_lds((const __attribute__((address_space(1))) void*)g,
                                     (__attribute__((address_space(3))) void*)l, 16, 0, 0);
}

__device__ __forceinline__ float gelu_f(float xx) {
    const float a = 0.7978845608f * (xx + 0.044715f * xx * xx * xx);
    const float t2 = 1.0f - 2.0f / (1.0f + __expf(2.0f * a));   // tanh(a)
    return 0.5f * xx * (1.0f + t2);
}

// ---------- 8-wave GEMM, 3-buffer depth-2, counted vmcnt, ONE barrier/K-tile,
// hoisted addressing (r16 + G7): per-wave global src pointers advance +32
// elems per stage; LDS dsts fixed slots + buffer stride; read offsets const.
// BM=256: 4Mx2N waves (per-wave 64x64), PER=3. BM=128: 2Mx4N (64x32), PER=2.
// Staging/read lane maps: r7-proven conflict-free XOR chunks.
template<int BM, int OUTBF, int RES, int GELU>
__global__ __launch_bounds__(512)
void gemm8p(const ushort* __restrict__ A, const ushort* __restrict__ W,
            const float* __restrict__ bias, const float* resid, void* outp,
            int M, int N, int K, int gx)
{
    constexpr int NCA = BM / 16;            // A chunks per K-tile (16 or 8)
    constexpr int NCB = 8;                  // B chunks (BN=128)
    constexpr int NCH = NCA + NCB;
    constexpr int PER = NCH / 8;            // loads per wave per K-tile (3 or 2)
    constexpr int WM  = (BM == 256) ? 4 : 2;
    constexpr int WN  = 8 / WM;
    constexpr int NI  = BM / 16 / WM;       // 4 in both configs
    constexpr int NJ  = 128 / 16 / WN;      // 4 (BM=256) or 2 (BM=128)
    constexpr int BUFS = NCH * 512;         // ushorts per buffer
    __shared__ __align__(16) ushort LS[3][BUFS];   // A chunks then B chunks

    const int tid  = threadIdx.x;
    const int lane = tid & 63, wid = tid >> 6;          // 8 waves

    // bijective XCD-aware swizzle (m204)
    const int nwg  = gridDim.x;
    const int orig = blockIdx.x;
    const int xcd = orig & 7, local = orig >> 3;
    const int q8 = nwg >> 3, r8 = nwg & 7;
    const int swz = (xcd < r8 ? xcd * (q8 + 1) : r8 * (q8 + 1) + (xcd - r8) * q8) + local;
    const int bx = swz % gx, by = swz / gx;

    const int m0 = by * BM, n0 = bx * 128;
    const int wr = wid / WN, wc = wid % WN;
    const int ecol = lane & 15, eg = lane >> 4;

    // r7-proven staging map: lane l -> slot l; fetch (row,kc) = dec of swizzle
    const int dec  = lane ^ ((lane >> 3) & 7);
    const int srow = dec >> 2;
    const int scol = (dec & 3) * 8;
    const int sfrag = ecol * 4 + eg;
    const int swslot = sfrag ^ ((sfrag >> 3) & 7);

    f32x4 acc[NI][NJ] = {};

    // hoisted per-wave staging pointers; chunks: A q=0..NCA-1, B q=NCA..NCH-1.
    const ushort* gsrc[PER];
    ushort* ldst[PER];
#pragma unroll
    for (int c = 0; c < PER; ++c) {
        const int q = wid * PER + c;
        if (q < NCA) {
            int ga = m0 + q * 16 + srow; if (ga > M - 1) ga = M - 1;   // clamp once
            gsrc[c] = A + (size_t)ga * K + scol;
        } else {
            const int rg = q - NCA;
            gsrc[c] = W + (size_t)(n0 + rg * 16 + srow) * K + scol;
        }
        ldst[c] = &LS[0][q * 512];
    }

    auto stage = [&](int p) {
#pragma unroll
        for (int c = 0; c < PER; ++c) {
            gload_lds16(gsrc[c], ldst[c] + p * BUFS);
            gsrc[c] += 32;                 // advance one K-tile (64B)
        }
    };

    // hoisted read offsets (const per thread -> registers after unroll)
    int aoff[NI], boff[NJ];
#pragma unroll
    for (int i = 0; i < NI; ++i) aoff[i] = (wr * NI + i) * 512 + swslot * 8;
#pragma unroll
    for (int j = 0; j < NJ; ++j) boff[j] = (NCA + wc * NJ + j) * 512 + swslot * 8;

    const int NT = K >> 5;                 // BK=32
    stage(0);
    stage(1);

    for (int t = 0; t < NT; ++t) {
        if (t + 1 < NT) asm volatile("s_waitcnt vmcnt(%0)" :: "n"(PER) : "memory");
        else            asm volatile("s_waitcnt vmcnt(0)" ::: "memory");
        __builtin_amdgcn_s_barrier();
        const ushort* cb = LS[t % 3];
        if (t + 2 < NT) stage((t + 2) % 3);   // buf of t-1: readers done pre-barrier
        bf16x8 af[NI], bfr[NJ];
#pragma unroll
        for (int i = 0; i < NI; ++i) af[i] = *(const bf16x8*)&cb[aoff[i]];
#pragma unroll
        for (int j = 0; j < NJ; ++j) bfr[j] = *(const bf16x8*)&cb[boff[j]];
        __builtin_amdgcn_s_setprio(1);
#pragma unroll
        for (int i = 0; i < NI; ++i)
#pragma unroll
            for (int j = 0; j < NJ; ++j)
                acc[i][j] = MFMA16(af[i], bfr[j], acc[i][j]);
        __builtin_amdgcn_s_setprio(0);
    }

#pragma unroll
    for (int i = 0; i < NI; ++i) {
        const int mb = m0 + wr * (NI * 16) + i * 16 + eg * 4;
#pragma unroll
        for (int j = 0; j < NJ; ++j) {
            const int n = n0 + wc * (NJ * 16) + j * 16 + ecol;
            const float bv = bias[n];
#pragma unroll
            for (int r = 0; r < 4; ++r) {
                const int m = mb + r;
                if (m < M) {
                    float v = acc[i][j][r] + bv;
                    if (RES)  v += resid[(size_t)m * N + n];
                    if (GELU) v = gelu_f(v);
                    if (OUTBF) ((ushort*)outp)[(size_t)m * N + n] = f2b(v);
                    else       ((float*)outp)[(size_t)m * N + n]  = v;
                }
            }
        }
    }
}

// ---------- 4-wave 2-phase GEMM (r10-proven; patch embed + proj) ----------
template<int BM, int BN, int OUTBF, int RES, int GELU>
__global__ __launch_bounds__(256)
void gemm_bt(const ushort* __restrict__ A, const ushort* __restrict__ W,
             const float* __restrict__ bias, const float* resid,
             void* outp, int M, int N, int K, int gx)
{
    constexpr int NI   = BM / 32;
    constexpr int NJ   = BN / 32;
    constexpr int NCHA = BM / 16;
    constexpr int NCHB = BN / 16;
    constexpr int NCH  = 2 * (NCHA + NCHB);
    constexpr int PER  = NCH / 4;
    __shared__ __align__(16) ushort Als[2][2 * NCHA * 512];
    __shared__ __align__(16) ushort Bls[2][2 * NCHB * 512];

    const int tid  = threadIdx.x;
    const int lane = tid & 63, wid = tid >> 6;

    const int nwg  = gridDim.x;
    const int orig = blockIdx.x;
    const int xcd = orig & 7, local = orig >> 3;
    const int q8 = nwg >> 3, r8 = nwg & 7;
    const int swz = (xcd < r8 ? xcd * (q8 + 1) : r8 * (q8 + 1) + (xcd - r8) * q8) + local;
    const int bx = swz % gx, by = swz / gx;

    const int m0 = by * BM, n0 = bx * BN;
    const int wr = wid >> 1, wc = wid & 1;
    const int ecol = lane & 15, eg = lane >> 4;

    const int dec  = lane ^ ((lane >> 3) & 7);
    const int srow = dec >> 2;
    const int scol = (dec & 3) * 8;
    const int sfrag = ecol * 4 + eg;
    const int swslot = sfrag ^ ((sfrag >> 3) & 7);

    f32x4 acc[NI][NJ] = {};

    auto stage = [&](int p, int k0) {
#pragma unroll
        for (int c = 0; c < PER; ++c) {
            const int q = wid * PER + c;
            if (q < 2 * NCHA) {
                const int rg = q >> 1, kh = q & 1;
                int ga = m0 + rg * 16 + srow; if (ga > M - 1) ga = M - 1;
                gload_lds16(A + (size_t)ga * K + k0 + kh * 32 + scol, &Als[p][q * 512]);
            } else {
                const int qq = q - 2 * NCHA;
                const int rg = qq >> 1, kh = qq & 1;
                gload_lds16(W + (size_t)(n0 + rg * 16 + srow) * K + k0 + kh * 32 + scol,
                            &Bls[p][qq * 512]);
            }
        }
    };

    const int NT = K >> 6;
    stage(0, 0);
    __syncthreads();

    int cur = 0;
    for (int t = 0; t < NT; ++t) {
        if (t + 1 < NT) stage(cur ^ 1, (t + 1) << 6);
#pragma unroll
        for (int kk = 0; kk < 2; ++kk) {
            bf16x8 af[NI], bfr[NJ];
#pragma unroll
            for (int i = 0; i < NI; ++i)
                af[i] = *(const bf16x8*)&Als[cur][(((wr * NI + i) << 1) + kk) * 512 + swslot * 8];
#pragma unroll
            for (int j = 0; j < NJ; ++j)
                bfr[j] = *(const bf16x8*)&Bls[cur][(((wc * NJ + j) << 1) + kk) * 512 + swslot * 8];
#pragma unroll
            for (int i = 0; i < NI; ++i)
#pragma unroll
                for (int j = 0; j < NJ; ++j)
                    acc[i][j] = MFMA16(af[i], bfr[j], acc[i][j]);
        }
        if (t + 1 < NT) __syncthreads();
        cur ^= 1;
    }

#pragma unroll
    for (int i = 0; i < NI; ++i) {
        const int mb = m0 + wr * (BM / 2) + i * 16 + eg * 4;
#pragma unroll
        for (int j = 0; j < NJ; ++j) {
            const int n = n0 + wc * (BN / 2) + j * 16 + ecol;
            const float bv = bias[n];
#pragma unroll
            for (int r = 0; r < 4; ++r) {
                const int m = mb + r;
                if (m < M) {
                    float v = acc[i][j][r] + bv;
                    if (RES)  v += resid[(size_t)m * N + n];
                    if (GELU) v = gelu_f(v);
                    if (OUTBF) ((ushort*)outp)[(size_t)m * N + n] = f2b(v);
                    else       ((float*)outp)[(size_t)m * N + n]  = v;
                }
            }
        }
    }
}

// ---------- attention: one block per (b, head), 4 waves, q-tiles of 16 ----------
__global__ __launch_bounds__(256)
void attn_k(const ushort* __restrict__ qkv, ushort* __restrict__ o)
{
    __shared__ __align__(16) ushort Vt[64][224];
    __shared__ __align__(16) ushort Pb[4][16][224];
    const int bh = blockIdx.x;
    const int b = bh / 12, hh = bh % 12;
    const int tid = threadIdx.x, lane = tid & 63, wid = tid >> 6;
    const size_t rs = 2304;
    const ushort* qb = qkv + (size_t)b * 197 * rs + hh * 64;
    const ushort* kb = qb + 768;
    const ushort* vb = qb + 1536;

    for (int i = tid; i < 197 * 64; i += 256) {
        const int s = i >> 6, d = i & 63;
        Vt[d][s] = vb[(size_t)s * rs + d];
    }
    for (int i = tid; i < 64 * 27; i += 256) {
        const int d = i / 27, s = 197 + i % 27;
        Vt[d][s] = 0;
    }
    __syncthreads();

    const int ecol = lane & 15, eg = lane >> 4;
    const bool m12bad = (192 + ecol) > 196;

    for (int qt = wid; qt < 13; qt += 4) {
        int qrow = qt * 16 + ecol; if (qrow > 196) qrow = 196;
        bf16x8 qa0 = *(const bf16x8*)&qb[(size_t)qrow * rs + eg * 8];
        bf16x8 qa1 = *(const bf16x8*)&qb[(size_t)qrow * rs + 32 + eg * 8];

        f32x4 s[13];
#pragma unroll
        for (int kt = 0; kt < 13; ++kt) {
            int krow = kt * 16 + ecol; if (krow > 196) krow = 196;
            bf16x8 kf0 = *(const bf16x8*)&kb[(size_t)krow * rs + eg * 8];
            bf16x8 kf1 = *(const bf16x8*)&kb[(size_t)krow * rs + 32 + eg * 8];
            f32x4 a = {};
            a = MFMA16(qa0, kf0, a);
            a = MFMA16(qa1, kf1, a);
            s[kt] = a;
        }
#pragma unroll
        for (int kt = 0; kt < 13; ++kt)
#pragma unroll
            for (int r = 0; r < 4; ++r) s[kt][r] *= 0.125f;
        if (m12bad) { s[12][0] = -1e30f; s[12][1] = -1e30f; s[12][2] = -1e30f; s[12][3] = -1e30f; }

#pragma unroll
        for (int r = 0; r < 4; ++r) {
            float mx = s[0][r];
#pragma unroll
            for (int kt = 1; kt < 13; ++kt) mx = fmaxf(mx, s[kt][r]);
#pragma unroll
            for (int off = 1; off < 16; off <<= 1) mx = fmaxf(mx, __shfl_xor(mx, off));
            float sm = 0.0f;
#pragma unroll
            for (int kt = 0; kt < 13; ++kt) { float e = __expf(s[kt][r] - mx); s[kt][r] = e; sm += e; }
#pragma unroll
            for (int off = 1; off < 16; off <<= 1) sm += __shfl_xor(sm, off);
            const float inv = 1.0f / sm;
#pragma unroll
            for (int kt = 0; kt < 13; ++kt) s[kt][r] *= inv;
        }

#pragma unroll
        for (int kt = 0; kt < 13; ++kt)
#pragma unroll
            for (int r = 0; r < 4; ++r)
                Pb[wid][eg * 4 + r][kt * 16 + ecol] = f2b(s[kt][r]);
#pragma unroll
        for (int r = 0; r < 4; ++r) Pb[wid][eg * 4 + r][208 + ecol] = 0;
        asm volatile("s_waitcnt lgkmcnt(0)" ::: "memory");
        __builtin_amdgcn_sched_barrier(0);

        f32x4 oacc[4] = {};
#pragma unroll
        for (int ks = 0; ks < 7; ++ks) {
            bf16x8 pa = *(const bf16x8*)&Pb[wid][ecol][ks * 32 + eg * 8];
#pragma unroll
            for (int dt = 0; dt < 4; ++dt) {
                bf16x8 vf = *(const bf16x8*)&Vt[dt * 16 + ecol][ks * 32 + eg * 8];
                oacc[dt] = MFMA16(pa, vf, oacc[dt]);
            }
        }
#pragma unroll
        for (int dt = 0; dt < 4; ++dt)
#pragma unroll
            for (int r = 0; r < 4; ++r) {
                const int q = qt * 16 + eg * 4 + r;
                if (q < 197)
                    o[((size_t)(b * 197 + q)) * 768 + hh * 64 + dt * 16 + ecol] = f2b(oacc[dt][r]);
            }
        asm volatile("s_waitcnt lgkmcnt(0)" ::: "memory");
        __builtin_amdgcn_sched_barrier(0);
    }
}

// ---------- LayerNorm (f32 in, bf16 out), one wave per row of 768 ----------
__global__ __launch_bounds__(256)
void ln_k(const float* __restrict__ x, const float* __restrict__ g,
          const float* __restrict__ bta, ushort* __restrict__ y, int rows)
{
    const int row  = blockIdx.x * 4 + (threadIdx.x >> 6);
    const int lane = threadIdx.x & 63;
    if (row >= rows) return;
    const float* xr = x + (size_t)row * 768;
    f32x4 v[3];
#pragma unroll
    for (int t = 0; t < 3; ++t) v[t] = *(const f32x4*)&xr[(lane + t * 64) * 4];
    float s = 0.0f;
#pragma unroll
    for (int t = 0; t < 3; ++t) s += v[t][0] + v[t][1] + v[t][2] + v[t][3];
#pragma unroll
    for (int off = 1; off < 64; off <<= 1) s += __shfl_xor(s, off);
    const float mean = s * (1.0f / 768.0f);
    float sq = 0.0f;
#pragma unroll
    for (int t = 0; t < 3; ++t)
#pragma unroll
        for (int c = 0; c < 4; ++c) { const float d = v[t][c] - mean; sq += d * d; }
#pragma unroll
    for (int off = 1; off < 64; off <<= 1) sq += __shfl_xor(sq, off);
    const float rstd = rsqrtf(sq * (1.0f / 768.0f) + 1e-5f);
    ushort* yr = y + (size_t)row * 768;
#pragma unroll
    for (int t = 0; t < 3; ++t) {
        const int c0 = (lane + t * 64) * 4;
        f32x4 gw = *(const f32x4*)&g[c0];
        f32x4 bb = *(const f32x4*)&bta[c0];
        u16x4 ov;
#pragma unroll
        for (int c = 0; c < 4; ++c) ov[c] = f2b((v[t][c] - mean) * rstd * gw[c] + bb[c]);
        *(u16x4*)&yr[c0] = ov;
    }
}

// ---------- im2col: x f32 -> patches bf16 [6272][768] ----------
__global__ void im2col_k(const float* __restrict__ x, ushort* __restrict__ p)
{
    const int gid = blockIdx.x * 256 + threadIdx.x;
    if (gid >= 6272 * 768) return;
    const int m = gid / 768, idx = gid - m * 768;
    const int b = m / 196, t = m - b * 196;
    const int gy = t / 14, gx = t - gy * 14;
    const int c = idx >> 8, rr = idx & 255;
    const int py = rr >> 4, px = rr & 15;
    const float v = x[(((size_t)(b * 3 + c) * 224) + gy * 16 + py) * 224 + gx * 16 + px];
    p[gid] = f2b(v);
}

// ---------- assemble: h = concat(cls, emb) + pos (all f32) ----------
__global__ void assemble_k(const float* __restrict__ emb, const float* __restrict__ cls,
                           const float* __restrict__ pos, float* __restrict__ h)
{
    const int gid = blockIdx.x * 256 + threadIdx.x;
    if (gid >= 6304 * 192) return;
    const int r = gid / 192, c4 = gid - r * 192;
    const int b = r / 197, s = r - b * 197;
    f32x4 pe = *(const f32x4*)&pos[(s * 192 + c4) * 4];
    f32x4 sv;
    if (s == 0) sv = *(const f32x4*)&cls[c4 * 4];
    else        sv = *(const f32x4*)&emb[((size_t)(b * 196 + (s - 1)) * 192 + c4) * 4];
    f32x4 ov = pe + sv;
    *(f32x4*)&h[(size_t)gid * 4] = ov;
}

// ---------- generic f32 -> bf16 convert (8 elems/thread) ----------
__global__ void cvt_k(const float* __restrict__ src, ushort* __restrict__ dst, int n8)
{
    const int g = blockIdx.x * 256 + threadIdx.x;
    if (g >= n8) return;
    const int e = g * 8;
    f32x4 a = *(const f32x4*)&src[e];
    f32x4 b = *(const f32x4*)&src[e + 4];
    u16x8 ov;
#pragma unroll
    for (int c = 0; c < 4; ++c) { ov[c] = f2b(a[c]); ov[4 + c] = f2b(b[c]); }
    *(u16x8*)&dst[e] = ov;
}

// ---------- fused per-layer weight convert + qkv-bias concat ----------
__global__ void conv6_k(const float* __restrict__ s0, const float* __restrict__ s1,
                        const float* __restrict__ s2, const float* __restrict__ s3,
                        const float* __restrict__ s4, const float* __restrict__ s5,
                        ushort* __restrict__ dst,
                        const float* __restrict__ bq, const float* __restrict__ bk,
                        const float* __restrict__ bv, float* __restrict__ b3)
{
    const int g = blockIdx.x * 256 + threadIdx.x;
    if (g >= 884736) {                       // bias-concat tail (2304 elems)
        const int i = g - 884736;
        if (i < 2304)
            b3[i] = (i < 768) ? bq[i] : (i < 1536 ? bk[i - 768] : bv[i - 1536]);
        return;
    }
    const int e = g * 8;
    const float* src; int off;
    if      (e < 589824)  { src = s0; off = e; }
    else if (e < 1179648) { src = s1; off = e - 589824; }
    else if (e < 1769472) { src = s2; off = e - 1179648; }
    else if (e < 2359296) { src = s3; off = e - 1769472; }
    else if (e < 4718592) { src = s4; off = e - 2359296; }
    else                  { src = s5; off = e - 4718592; }
    f32x4 a = *(const f32x4*)&src[off];
    f32x4 b = *(const f32x4*)&src[off + 4];
    u16x8 ov;
#pragma unroll
    for (int c = 0; c < 4; ++c) { ov[c] = f2b(a[c]); ov[4 + c] = f2b(b[c]); }
    *(u16x8*)&dst[e] = ov;
}

// ---------- classifier: logits[b,n] from h[b*197] row, f32 out ----------
__global__ __launch_bounds__(64)
void clf_k(const float* __restrict__ h, const float* __restrict__ w,
           const float* __restrict__ bias, float* __restrict__ out)
{
    const int b = blockIdx.x, lane = threadIdx.x;
    const float* hr = h + (size_t)b * 197 * 768;
    float hv[12];
#pragma unroll
    for (int j = 0; j < 12; ++j) hv[j] = hr[lane + j * 64];
    for (int n = 0; n < 14; ++n) {
        float sm = 0.0f;
#pragma unroll
        for (int j = 0; j < 12; ++j) sm += hv[j] * w[n * 768 + lane + j * 64];
#pragma unroll
        for (int off = 1; off < 64; off <<= 1) sm += __shfl_xor(sm, off);
        if (lane == 0) out[b * 14 + n] = sm + bias[n];
    }
}

// ---------- launcher ----------
extern "C" void kernel_launch(void* const* d_in, const int* in_sizes, int n_in,
                              void* d_out, int out_size, void* d_ws, size_t ws_size,
                              hipStream_t stream)
{
    const float* x       = (const float*)d_in[0];
    const float* patch_w = (const float*)d_in[1];
    const float* patch_b = (const float*)d_in[2];
    const float* cls_tok = (const float*)d_in[3];
    const float* pos_emb = (const float*)d_in[4];
    const float* ln1_w   = (const float*)d_in[5];
    const float* ln1_b   = (const float*)d_in[6];
    const float* wq      = (const float*)d_in[7];
    const float* bq      = (const float*)d_in[8];
    const float* wk      = (const float*)d_in[9];
    const float* bk      = (const float*)d_in[10];
    const float* wv      = (const float*)d_in[11];
    const float* bv      = (const float*)d_in[12];
    const float* wo      = (const float*)d_in[13];
    const float* bo      = (const float*)d_in[14];
    const float* ln2_w   = (const float*)d_in[15];
    const float* ln2_b   = (const float*)d_in[16];
    const float* fc1w    = (const float*)d_in[17];
    const float* fc1b    = (const float*)d_in[18];
    const float* fc2w    = (const float*)d_in[19];
    const float* fc2b    = (const float*)d_in[20];
    const float* clfw    = (const float*)d_in[21];
    const float* clfb    = (const float*)d_in[22];

    char* ws = (char*)d_ws;
    float*  h    = (float*)(ws + 0);                    // 6304*768 f32
    ushort* y    = (ushort*)(ws + 19365888);            // 6304*768 bf16
    ushort* qkv  = (ushort*)(ws + 29048832);            // 6304*2304 bf16
    ushort* o    = (ushort*)(ws + 58097664);            // 6304*768 bf16
    ushort* ff   = (ushort*)(ws + 67780608);            // 6304*3072 bf16
    ushort* wbuf = (ushort*)(ws + 106512384);           // 7,077,888 bf16 (per-layer)
    float*  b3   = (float*)(ws + 120668160);            // 2304 f32
    ushort* patches = (ushort*)(ws + 67780608);         // alias ff (used pre-loop)
    float*  emb     = (float*)(ws + 67780608 + 16777216); // alias ff+16MB

    // patch embed
    im2col_k<<<18816, 256, 0, stream>>>(x, patches);
    cvt_k<<<288, 256, 0, stream>>>(patch_w, wbuf, 73728);
    gemm_bt<128, 64, 0, 0, 0><<<12 * 49, 256, 0, stream>>>(patches, wbuf, patch_b,
                                                      (const float*)nullptr, (void*)emb, 6272, 768, 768, 12);
    assemble_k<<<4728, 256, 0, stream>>>(emb, cls_tok, pos_emb, h);

    for (int l = 0; l < 12; ++l) {
        conv6_k<<<3466, 256, 0, stream>>>(wq + (size_t)l * 589824, wk + (size_t)l * 589824,
                                          wv + (size_t)l * 589824, wo + (size_t)l * 589824,
                                          fc1w + (size_t)l * 2359296, fc2w + (size_t)l * 2359296, wbuf,
                                          bq + l * 768, bk + l * 768, bv + l * 768, b3);
        ln_k<<<1576, 256, 0, stream>>>(h, ln1_w + l * 768, ln1_b + l * 768, y, 6304);
        gemm8p<256, 1, 0, 0><<<18 * 25, 512, 0, stream>>>(y, wbuf, b3,
                                                          (const float*)nullptr, (void*)qkv, 6304, 2304, 768, 18);
        attn_k<<<384, 256, 0, stream>>>(qkv, o);
        gemm_bt<128, 64, 0, 1, 0><<<12 * 50, 256, 0, stream>>>(o, wbuf + 1769472, bo + l * 768,
                                                          (const float*)h, (void*)h, 6304, 768, 768, 12);
        ln_k<<<1576, 256, 0, stream>>>(h, ln2_w + l * 768, ln2_b + l * 768, y, 6304);
        gemm8p<256, 1, 0, 1><<<24 * 25, 512, 0, stream>>>(y, wbuf + 2359296, fc1b + (size_t)l * 3072,
                                                          (const float*)nullptr, (void*)ff, 6304, 3072, 768, 24);
        gemm8p<128, 0, 1, 0><<<6 * 50, 512, 0, stream>>>(ff, wbuf + 4718592, fc2b + l * 768,
                                                         (const float*)h, (void*)h, 6304, 768, 3072, 6);
    }
    clf_k<<<32, 64, 0, stream>>>(h, clfw, clfb, (float*)d_out);
}